// Round 2
// baseline (732.280 us; speedup 1.0000x reference)
//
#include <hip/hip_runtime.h>

#define D_NODE 128
#define D_EDGE 64
#define D_IN   192
#define NEG    0.01f
#define LN_EPS 1e-5f

typedef short bf16x8 __attribute__((ext_vector_type(8)));
typedef float f32x4  __attribute__((ext_vector_type(4)));

__device__ __forceinline__ unsigned f2bf(float f) {
    unsigned u = __builtin_bit_cast(unsigned, f);
    return (u + 0x7FFFu + ((u >> 16) & 1u)) >> 16;   // RNE
}
__device__ __forceinline__ unsigned pk2(float a, float b) {
    return f2bf(a) | (f2bf(b) << 16);
}

// ---------------------------------------------------------------------------
// Pre-pack x (N x 128 f32) -> bf16 once.
// ---------------------------------------------------------------------------
__global__ void k_packx(const float* __restrict__ x, unsigned short* __restrict__ xb,
                        int n8) {
    int i = blockIdx.x * blockDim.x + threadIdx.x;
    int stride = gridDim.x * blockDim.x;
    for (int t = i; t < n8; t += stride) {
        const float4* p = (const float4*)x + (size_t)t * 2;
        float4 a = p[0], b = p[1];
        uint4 o;
        o.x = pk2(a.x, a.y); o.y = pk2(a.z, a.w);
        o.z = pk2(b.x, b.y); o.w = pk2(b.z, b.w);
        ((uint4*)xb)[t] = o;
    }
}

// ---------------------------------------------------------------------------
// Counting sort of edges by destination: hist -> exclusive scan -> bucket.
// ---------------------------------------------------------------------------
__global__ void k_hist(const int* __restrict__ ei, int* __restrict__ hist, int E) {
    int i = blockIdx.x * blockDim.x + threadIdx.x;
    int stride = gridDim.x * blockDim.x;
    for (int e = i; e < E; e += stride) atomicAdd(&hist[ei[E + e]], 1);
}

__global__ __launch_bounds__(1024) void k_scanA(const int* __restrict__ hist,
                                                int* __restrict__ base,
                                                int* __restrict__ blockTot, int N) {
    __shared__ int wsum[16], woff[16];
    const int t = threadIdx.x, b = blockIdx.x;
    const int i = b * 1024 + t;
    const int lane = t & 63, w = t >> 6;
    int v = (i < N) ? hist[i] : 0;
    int x = v;
    #pragma unroll
    for (int d = 1; d < 64; d <<= 1) { int u = __shfl_up(x, d); if (lane >= d) x += u; }
    if (lane == 63) wsum[w] = x;
    __syncthreads();
    if (t < 16) {
        int y = wsum[t];
        #pragma unroll
        for (int d = 1; d < 16; d <<= 1) { int u = __shfl_up(y, d, 16); if (t >= d) y += u; }
        woff[t] = y - wsum[t];
    }
    __syncthreads();
    int incl = x + woff[w];
    if (i < N) base[i] = incl - v;            // exclusive within block
    if (t == 1023) blockTot[b] = incl;
}

__global__ void k_scanB(int* __restrict__ blockTot, int NB) {   // 1 block, 64 thr, NB<=64
    int t = threadIdx.x;
    int v = (t < NB) ? blockTot[t] : 0;
    int x = v;
    #pragma unroll
    for (int d = 1; d < 64; d <<= 1) { int u = __shfl_up(x, d); if (t >= d) x += u; }
    if (t < NB) blockTot[t] = x - v;          // exclusive block offsets
}

__global__ __launch_bounds__(1024) void k_scanC(int* __restrict__ base,
                                                const int* __restrict__ blockTot, int N) {
    int i = blockIdx.x * 1024 + threadIdx.x;
    if (i < N) base[i] += blockTot[blockIdx.x];
}

__global__ void k_bucket(const int* __restrict__ ei, int* __restrict__ base,
                         int* __restrict__ perm, int* __restrict__ srcrow,
                         int* __restrict__ dstcol, int E) {
    int i = blockIdx.x * blockDim.x + threadIdx.x;
    int stride = gridDim.x * blockDim.x;
    for (int e = i; e < E; e += stride) {
        int c = ei[E + e];
        int r = ei[e];
        int p = atomicAdd(&base[c], 1);       // consumes base (cursor)
        perm[p]   = e;
        srcrow[p] = r;
        dstcol[p] = c;
    }
}

// ---------------------------------------------------------------------------
// Edge kernel over DEST-SORTED edges, 64-edge tiles, SOFTWARE-PIPELINED:
//   tile t+1's gathers (xb rows, edge_attr rows, dstcol) are issued into
//   REGISTERS right after B1 of tile t, so their ~900cy HBM latency hides
//   under MFMA + LN + MFMA-reduce of tile t (T14 async-STAGE split).
//   Pipeline: regs->LDS write | B1 | issue next gathers | MFMA y=h@W1+b1 |
//   LN partials | B2 | PT build + LN finalize + yT | B3 | MFMA seg-reduce |
//   stores | B4.
// ---------------------------------------------------------------------------
__global__ __launch_bounds__(256, 4) void edge_mfma_seg(
    const unsigned short* __restrict__ xb,
    const float* __restrict__ edge_attr,
    const int*   __restrict__ perm,
    const int*   __restrict__ srcrow,
    const int*   __restrict__ dstcol,
    const float* __restrict__ W1,
    const float* __restrict__ b1,
    const float* __restrict__ g1,
    const float* __restrict__ be1,
    float* __restrict__ sums,
    int E, int ntiles)
{
    __shared__ __align__(16) unsigned short h[64][200];   // 25600 B; reused for yT+PT
    __shared__ float rS [64][4], rS2[64][4];
    __shared__ int   scol[64];
    __shared__ int   rdest[64];
    __shared__ int   nruns_sh;

    unsigned short (*yT)[64] = (unsigned short (*)[64])(&h[0][0]);
    unsigned short (*PT)[64] = (unsigned short (*)[64])((char*)(&h[0][0]) + 16384);

    const int tid = threadIdx.x;
    const int w   = tid >> 6;
    const int l   = tid & 63;
    const int lm  = l & 15;
    const int q   = l >> 4;
    const int q8  = q * 8;
    const int e   = tid >> 2;
    const int qq  = tid & 3;

    // W1 fragments, bias/gamma/beta for this wave's 32 cols (once per block)
    bf16x8 Bfr[2][6];
    float  b1v[2], g1v[2], bev[2];
    #pragma unroll
    for (int c2 = 0; c2 < 2; ++c2) {
        const int n = (2 * w + c2) * 16 + lm;
        b1v[c2] = b1[n]; g1v[c2] = g1[n]; bev[c2] = be1[n];
        #pragma unroll
        for (int kt = 0; kt < 6; ++kt) {
            bf16x8 f;
            #pragma unroll
            for (int j = 0; j < 8; ++j)
                f[j] = (short)f2bf(W1[(kt * 32 + q8 + j) * 128 + n]);
            Bfr[c2][kt] = f;
        }
    }

    const int stride_t = gridDim.x;
    int tile = blockIdx.x;                    // < ntiles (grid is clamped)

    // ---- prologue: stage tile `tile` into registers ----
    uint4  xr0, xr1, xr2, xr3;
    float4 af0, af1, af2, af3;
    int    sc;
    bool   vld;
    {
        const int ge = tile * 64 + e;
        vld = (ge < E);
        if (vld) {
            const int row = srcrow[ge];
            const int eid = perm[ge];
            const uint4* xr = (const uint4*)(xb + (size_t)row * D_NODE) + qq * 4;
            xr0 = xr[0]; xr1 = xr[1]; xr2 = xr[2]; xr3 = xr[3];
            const float4* ar = (const float4*)(edge_attr + (size_t)eid * D_EDGE) + qq * 4;
            af0 = ar[0]; af1 = ar[1]; af2 = ar[2]; af3 = ar[3];
        }
        sc = (tid < 64 && tile * 64 + tid < E) ? dstcol[tile * 64 + tid] : -1;
    }

    for (; tile < ntiles; tile += stride_t) {
        // ---- staged regs -> LDS (vmcnt wait for prefetch lands here) ----
        if (vld) {
            *(uint4*)&h[e][qq * 32 +  0] = xr0;
            *(uint4*)&h[e][qq * 32 +  8] = xr1;
            *(uint4*)&h[e][qq * 32 + 16] = xr2;
            *(uint4*)&h[e][qq * 32 + 24] = xr3;
            uint4 o;
            o.x = pk2(af0.x, af0.y); o.y = pk2(af0.z, af0.w);
            o.z = pk2(af1.x, af1.y); o.w = pk2(af1.z, af1.w);
            *(uint4*)&h[e][128 + qq * 16] = o;
            o.x = pk2(af2.x, af2.y); o.y = pk2(af2.z, af2.w);
            o.z = pk2(af3.x, af3.y); o.w = pk2(af3.z, af3.w);
            *(uint4*)&h[e][128 + qq * 16 + 8] = o;
        } else {
            uint4 z = make_uint4(0u, 0u, 0u, 0u);
            *(uint4*)&h[e][qq * 32 +  0] = z;
            *(uint4*)&h[e][qq * 32 +  8] = z;
            *(uint4*)&h[e][qq * 32 + 16] = z;
            *(uint4*)&h[e][qq * 32 + 24] = z;
            *(uint4*)&h[e][128 + qq * 16]     = z;
            *(uint4*)&h[e][128 + qq * 16 + 8] = z;
        }
        if (tid < 64) scol[tid] = sc;
        __syncthreads();                       // B1: h/scol ready

        // ---- issue NEXT tile's gathers into registers (hide under compute) ----
        {
            const int nt = tile + stride_t;
            const int ge = nt * 64 + e;
            vld = (nt < ntiles) && (ge < E);
            if (vld) {
                const int row = srcrow[ge];
                const int eid = perm[ge];
                const uint4* xr = (const uint4*)(xb + (size_t)row * D_NODE) + qq * 4;
                xr0 = xr[0]; xr1 = xr[1]; xr2 = xr[2]; xr3 = xr[3];
                const float4* ar = (const float4*)(edge_attr + (size_t)eid * D_EDGE) + qq * 4;
                af0 = ar[0]; af1 = ar[1]; af2 = ar[2]; af3 = ar[3];
            }
            sc = (nt < ntiles && tid < 64 && nt * 64 + tid < E)
                   ? dstcol[nt * 64 + tid] : -1;
        }

        // ---- MFMA: 4 edge-tiles x 2 col-tiles, K=192 ----
        f32x4 acc[4][2];
        #pragma unroll
        for (int et = 0; et < 4; ++et)
            #pragma unroll
            for (int c2 = 0; c2 < 2; ++c2)
                acc[et][c2] = (f32x4){0.f, 0.f, 0.f, 0.f};

        #pragma unroll
        for (int et = 0; et < 4; ++et) {
            bf16x8 Afr[6];
            #pragma unroll
            for (int kt = 0; kt < 6; ++kt)
                Afr[kt] = *(const bf16x8*)&h[et * 16 + lm][kt * 32 + q8];
            #pragma unroll
            for (int c2 = 0; c2 < 2; ++c2)
                #pragma unroll
                for (int kt = 0; kt < 6; ++kt)
                    acc[et][c2] = __builtin_amdgcn_mfma_f32_16x16x32_bf16(
                        Afr[kt], Bfr[c2][kt], acc[et][c2], 0, 0, 0);
        }

        // ---- bias + LN partial sums ----
        #pragma unroll
        for (int et = 0; et < 4; ++et) {
            #pragma unroll
            for (int r = 0; r < 4; ++r) {
                float v0 = acc[et][0][r] + b1v[0];
                float v1 = acc[et][1][r] + b1v[1];
                acc[et][0][r] = v0;
                acc[et][1][r] = v1;
                float s  = v0 + v1;
                float s2 = v0 * v0 + v1 * v1;
                #pragma unroll
                for (int off = 1; off < 16; off <<= 1) {
                    s  += __shfl_xor(s,  off, 16);
                    s2 += __shfl_xor(s2, off, 16);
                }
                if (lm == 0) {
                    const int em = et * 16 + q * 4 + r;
                    rS [em][w] = s;
                    rS2[em][w] = s2;
                }
            }
        }
        __syncthreads();                       // B2: rS ready; ALL h reads done

        // ---- wave 0: run metadata + selection matrix P^T ----
        if (tid < 64) {
            uint4 z = make_uint4(0u, 0u, 0u, 0u);
            #pragma unroll
            for (int i = 0; i < 8; ++i)
                *(uint4*)&PT[tid][i * 8] = z;
            int me = scol[tid];
            int pv = (tid == 0) ? (me ^ 1) : scol[tid - 1];   // force start at 0
            unsigned long long m = __ballot(me != pv);
            int run = __popcll(m & ((2ull << tid) - 1)) - 1;  // run id of edge tid
            if (me != pv) rdest[run] = me;
            if (tid == 0) nruns_sh = (int)__popcll(m);
            int ep = (tid & 7) | ((((tid >> 3) ^ (run & 7)) & 7) << 3);
            PT[run][ep] = 0x3F80;
        }

        // ---- finalize LN + LeakyReLU, write y^T (bf16, swizzled) ----
        #pragma unroll
        for (int et = 0; et < 4; ++et) {
            float yv[2][4];
            #pragma unroll
            for (int r = 0; r < 4; ++r) {
                const int em = et * 16 + q * 4 + r;
                float4 p  = *(const float4*)&rS [em][0];
                float4 p2 = *(const float4*)&rS2[em][0];
                const float S    = (p.x  + p.y)  + (p.z  + p.w);
                const float S2   = (p2.x + p2.y) + (p2.z + p2.w);
                const float mu   = S * (1.f / 128.f);
                const float var  = S2 * (1.f / 128.f) - mu * mu;
                const float rstd = rsqrtf(var + LN_EPS);
                #pragma unroll
                for (int c2 = 0; c2 < 2; ++c2) {
                    float y = (acc[et][c2][r] - mu) * rstd * g1v[c2] + bev[c2];
                    y = (y > 0.f) ? y : NEG * y;
                    yv[c2][r] = y;
                }
            }
            #pragma unroll
            for (int c2 = 0; c2 < 2; ++c2) {
                const int col = (2 * w + c2) * 16 + lm;
                const int em0 = et * 16 + q * 4;
                const int ch  = ((em0 >> 3) ^ (col & 7)) & 7;
                uint2 o;
                o.x = pk2(yv[c2][0], yv[c2][1]);
                o.y = pk2(yv[c2][2], yv[c2][3]);
                *(uint2*)&yT[col][ch * 8 + (q & 1) * 4] = o;
            }
        }
        __syncthreads();                       // B3: yT + PT + metadata ready

        // ---- segmented reduce via MFMA: D^T[col][run] ----
        {
            bf16x8 afr[2][2];
            #pragma unroll
            for (int ct = 0; ct < 2; ++ct)
                #pragma unroll
                for (int kt = 0; kt < 2; ++kt) {
                    const int col = w * 32 + ct * 16 + lm;
                    const int ch  = ((kt * 4 + q) ^ (col & 7)) & 7;
                    afr[ct][kt] = *(const bf16x8*)&yT[col][ch * 8];
                }
            const int nr = nruns_sh;
            for (int rt = 0; rt * 16 < nr; ++rt) {
                bf16x8 bfr[2];
                #pragma unroll
                for (int kt = 0; kt < 2; ++kt) {
                    const int rr = rt * 16 + lm;
                    const int ch = ((kt * 4 + q) ^ (rr & 7)) & 7;
                    bfr[kt] = *(const bf16x8*)&PT[rr][ch * 8];
                }
                f32x4 o0 = (f32x4){0.f, 0.f, 0.f, 0.f};
                f32x4 o1 = (f32x4){0.f, 0.f, 0.f, 0.f};
                #pragma unroll
                for (int kt = 0; kt < 2; ++kt) {
                    o0 = __builtin_amdgcn_mfma_f32_16x16x32_bf16(
                        afr[0][kt], bfr[kt], o0, 0, 0, 0);
                    o1 = __builtin_amdgcn_mfma_f32_16x16x32_bf16(
                        afr[1][kt], bfr[kt], o1, 0, 0, 0);
                }
                const int run = rt * 16 + lm;     // C layout: n = lane&15
                if (run < nr) {
                    const int dest = rdest[run];
                    if (dest >= 0) {
                        const bool at = (run == 0) || (run == nr - 1);
                        float* p0 = &sums[(size_t)dest * D_NODE + w * 32 + q * 4];
                        if (at) {
                            #pragma unroll
                            for (int r = 0; r < 4; ++r) {
                                atomicAdd(&p0[r],      o0[r]);
                                atomicAdd(&p0[16 + r], o1[r]);
                            }
                        } else {
                            *(f32x4*)p0        = o0;
                            *(f32x4*)(p0 + 16) = o1;
                        }
                    }
                }
            }
        }
        __syncthreads();                       // B4: protect h/scol/meta for next tile
    }
}

// ---------------------------------------------------------------------------
// Node kernel (MFMA): m = sums/cnt -> y = m@W2+b2 -> LN -> LeakyReLU
//                     -> +x -> LeakyReLU -> out.  64-node tiles.
// ---------------------------------------------------------------------------
__global__ __launch_bounds__(256) void node_mfma(
    const float* __restrict__ sums,
    const int*   __restrict__ hist,
    const float* __restrict__ x,
    const float* __restrict__ W2,
    const float* __restrict__ b2,
    const float* __restrict__ g2,
    const float* __restrict__ be2,
    float* __restrict__ out,
    int N)
{
    __shared__ __align__(16) unsigned short h[64][136];     // 17.4 KB
    __shared__ float rS [64][4], rS2[64][4];

    const int tid = threadIdx.x;
    const int w   = tid >> 6;
    const int l   = tid & 63;
    const int lm  = l & 15;
    const int q   = l >> 4;
    const int q8  = q * 8;

    bf16x8 Bfr[2][4];
    float  b2v[2], g2v[2], bev[2];
    #pragma unroll
    for (int c2 = 0; c2 < 2; ++c2) {
        const int n = (2 * w + c2) * 16 + lm;
        b2v[c2] = b2[n]; g2v[c2] = g2[n]; bev[c2] = be2[n];
        #pragma unroll
        for (int kt = 0; kt < 4; ++kt) {
            bf16x8 f;
            #pragma unroll
            for (int j = 0; j < 8; ++j)
                f[j] = (short)f2bf(W2[(kt * 32 + q8 + j) * 128 + n]);
            Bfr[c2][kt] = f;
        }
    }

    const int n0 = blockIdx.x * 64;

    // stage m = sums/cnt (bf16)
    {
        const int e  = tid >> 2;
        const int qq = tid & 3;
        const int gn = n0 + e;
        if (gn < N) {
            const int cnt = hist[gn];
            const float sc = (cnt > 0) ? 1.f / (float)cnt : 0.f;
            const float4* sr = (const float4*)(sums + (size_t)gn * D_NODE);
            #pragma unroll
            for (int i = 0; i < 8; ++i) {
                float4 v = sr[qq * 8 + i];
                *(uint2*)&h[e][qq * 32 + i * 4] =
                    make_uint2(pk2(v.x * sc, v.y * sc), pk2(v.z * sc, v.w * sc));
            }
        } else {
            #pragma unroll
            for (int i = 0; i < 8; ++i)
                *(uint2*)&h[e][qq * 32 + i * 4] = make_uint2(0u, 0u);
        }
    }
    __syncthreads();

    f32x4 acc[4][2];
    #pragma unroll
    for (int et = 0; et < 4; ++et)
        #pragma unroll
        for (int c2 = 0; c2 < 2; ++c2)
            acc[et][c2] = (f32x4){0.f, 0.f, 0.f, 0.f};

    #pragma unroll
    for (int et = 0; et < 4; ++et) {
        bf16x8 Afr[4];
        #pragma unroll
        for (int kt = 0; kt < 4; ++kt)
            Afr[kt] = *(const bf16x8*)&h[et * 16 + lm][kt * 32 + q8];
        #pragma unroll
        for (int c2 = 0; c2 < 2; ++c2)
            #pragma unroll
            for (int kt = 0; kt < 4; ++kt)
                acc[et][c2] = __builtin_amdgcn_mfma_f32_16x16x32_bf16(
                    Afr[kt], Bfr[c2][kt], acc[et][c2], 0, 0, 0);
    }

    #pragma unroll
    for (int et = 0; et < 4; ++et) {
        #pragma unroll
        for (int r = 0; r < 4; ++r) {
            float v0 = acc[et][0][r] + b2v[0];
            float v1 = acc[et][1][r] + b2v[1];
            acc[et][0][r] = v0;
            acc[et][1][r] = v1;
            float s  = v0 + v1;
            float s2 = v0 * v0 + v1 * v1;
            #pragma unroll
            for (int off = 1; off < 16; off <<= 1) {
                s  += __shfl_xor(s,  off, 16);
                s2 += __shfl_xor(s2, off, 16);
            }
            if (lm == 0) {
                const int em = et * 16 + q * 4 + r;
                rS [em][w] = s;
                rS2[em][w] = s2;
            }
        }
    }
    __syncthreads();

    #pragma unroll
    for (int et = 0; et < 4; ++et) {
        #pragma unroll
        for (int r = 0; r < 4; ++r) {
            const int em = et * 16 + q * 4 + r;
            const int gn = n0 + em;
            if (gn >= N) continue;
            float4 p  = *(const float4*)&rS [em][0];
            float4 p2 = *(const float4*)&rS2[em][0];
            const float S    = (p.x  + p.y)  + (p.z  + p.w);
            const float S2   = (p2.x + p2.y) + (p2.z + p2.w);
            const float mu   = S * (1.f / 128.f);
            const float var  = S2 * (1.f / 128.f) - mu * mu;
            const float rstd = rsqrtf(var + LN_EPS);
            #pragma unroll
            for (int c2 = 0; c2 < 2; ++c2) {
                const int col = (2 * w + c2) * 16 + lm;
                float y = (acc[et][c2][r] - mu) * rstd * g2v[c2] + bev[c2];
                y = (y > 0.f) ? y : NEG * y;
                float rr = y + x[(size_t)gn * D_NODE + col];
                rr = (rr > 0.f) ? rr : NEG * rr;
                out[(size_t)gn * D_NODE + col] = rr;
            }
        }
    }
}

// ---------------------------------------------------------------------------
extern "C" void kernel_launch(void* const* d_in, const int* in_sizes, int n_in,
                              void* d_out, int out_size, void* d_ws, size_t ws_size,
                              hipStream_t stream) {
    const float* x          = (const float*)d_in[0];
    const int*   edge_index = (const int*)  d_in[1];
    const float* edge_attr  = (const float*)d_in[2];
    const float* W1         = (const float*)d_in[3];
    const float* b1         = (const float*)d_in[4];
    const float* g1         = (const float*)d_in[5];
    const float* be1        = (const float*)d_in[6];
    const float* W2         = (const float*)d_in[7];
    const float* b2         = (const float*)d_in[8];
    const float* g2         = (const float*)d_in[9];
    const float* be2        = (const float*)d_in[10];

    const int N = in_sizes[0] / D_NODE;     // 50000
    const int E = in_sizes[1] / 2;          // 600000

    float* sums     = (float*)d_ws;                        // N*128 f32
    int*   hist     = (int*)(sums + (size_t)N * D_NODE);   // N
    int*   base     = hist + N;                            // N
    int*   blockTot = base + N;                            // 64
    int*   perm     = blockTot + 64;                       // E
    int*   srcrow   = perm + E;                            // E
    int*   dstcol   = srcrow + E;                          // E
    unsigned short* xb = (unsigned short*)(dstcol + E);    // N*128 bf16 (~46 MB total)

    // zero sums + hist in one shot
    hipMemsetAsync(d_ws, 0, ((size_t)N * D_NODE + (size_t)N) * sizeof(float), stream);

    const int n8 = N * (D_NODE / 8);
    k_packx<<<dim3(1024), dim3(256), 0, stream>>>(x, xb, n8);

    k_hist<<<dim3(256), dim3(256), 0, stream>>>(edge_index, hist, E);
    const int NB = (N + 1023) / 1024;                      // 49 (<=64)
    k_scanA<<<dim3(NB), dim3(1024), 0, stream>>>(hist, base, blockTot, N);
    k_scanB<<<dim3(1),  dim3(64),   0, stream>>>(blockTot, NB);
    k_scanC<<<dim3(NB), dim3(1024), 0, stream>>>(base, blockTot, N);
    k_bucket<<<dim3(256), dim3(256), 0, stream>>>(edge_index, base, perm, srcrow, dstcol, E);

    const int ntiles = (E + 63) / 64;
    const int grid   = ntiles < 1280 ? ntiles : 1280;
    edge_mfma_seg<<<dim3(grid), dim3(256), 0, stream>>>(
        xb, edge_attr, perm, srcrow, dstcol, W1, b1, g1, be1, sums, E, ntiles);

    node_mfma<<<dim3((N + 63) / 64), dim3(256), 0, stream>>>(
        sums, hist, x, W2, b2, g2, be2, (float*)d_out, N);
}

// Round 3
// 636.356 us; speedup vs baseline: 1.1507x; 1.1507x over previous
//
#include <hip/hip_runtime.h>

#define D_NODE 128
#define D_EDGE 64
#define D_IN   192
#define NEG    0.01f
#define LN_EPS 1e-5f

typedef short bf16x8 __attribute__((ext_vector_type(8)));
typedef float f32x4  __attribute__((ext_vector_type(4)));

__device__ __forceinline__ unsigned f2bf(float f) {
    unsigned u = __builtin_bit_cast(unsigned, f);
    return (u + 0x7FFFu + ((u >> 16) & 1u)) >> 16;   // RNE
}
__device__ __forceinline__ unsigned pk2(float a, float b) {
    return f2bf(a) | (f2bf(b) << 16);
}

// ---------------------------------------------------------------------------
// Pre-pack x (N x 128 f32) -> bf16 once.
// ---------------------------------------------------------------------------
__global__ void k_packx(const float* __restrict__ x, unsigned short* __restrict__ xb,
                        int n8) {
    int i = blockIdx.x * blockDim.x + threadIdx.x;
    int stride = gridDim.x * blockDim.x;
    for (int t = i; t < n8; t += stride) {
        const float4* p = (const float4*)x + (size_t)t * 2;
        float4 a = p[0], b = p[1];
        uint4 o;
        o.x = pk2(a.x, a.y); o.y = pk2(a.z, a.w);
        o.z = pk2(b.x, b.y); o.w = pk2(b.z, b.w);
        ((uint4*)xb)[t] = o;
    }
}

// ---------------------------------------------------------------------------
// Counting sort of edges by destination: hist -> exclusive scan -> bucket.
// ---------------------------------------------------------------------------
__global__ void k_hist(const int* __restrict__ ei, int* __restrict__ hist, int E) {
    int i = blockIdx.x * blockDim.x + threadIdx.x;
    int stride = gridDim.x * blockDim.x;
    for (int e = i; e < E; e += stride) atomicAdd(&hist[ei[E + e]], 1);
}

__global__ __launch_bounds__(1024) void k_scanA(const int* __restrict__ hist,
                                                int* __restrict__ base,
                                                int* __restrict__ blockTot, int N) {
    __shared__ int wsum[16], woff[16];
    const int t = threadIdx.x, b = blockIdx.x;
    const int i = b * 1024 + t;
    const int lane = t & 63, w = t >> 6;
    int v = (i < N) ? hist[i] : 0;
    int x = v;
    #pragma unroll
    for (int d = 1; d < 64; d <<= 1) { int u = __shfl_up(x, d); if (lane >= d) x += u; }
    if (lane == 63) wsum[w] = x;
    __syncthreads();
    if (t < 16) {
        int y = wsum[t];
        #pragma unroll
        for (int d = 1; d < 16; d <<= 1) { int u = __shfl_up(y, d, 16); if (t >= d) y += u; }
        woff[t] = y - wsum[t];
    }
    __syncthreads();
    int incl = x + woff[w];
    if (i < N) base[i] = incl - v;            // exclusive within block
    if (t == 1023) blockTot[b] = incl;
}

__global__ void k_scanB(int* __restrict__ blockTot, int NB) {   // 1 block, 64 thr, NB<=64
    int t = threadIdx.x;
    int v = (t < NB) ? blockTot[t] : 0;
    int x = v;
    #pragma unroll
    for (int d = 1; d < 64; d <<= 1) { int u = __shfl_up(x, d); if (t >= d) x += u; }
    if (t < NB) blockTot[t] = x - v;          // exclusive block offsets
}

__global__ __launch_bounds__(1024) void k_scanC(int* __restrict__ base,
                                                const int* __restrict__ blockTot, int N) {
    int i = blockIdx.x * 1024 + threadIdx.x;
    if (i < N) base[i] += blockTot[blockIdx.x];
}

// ---------------------------------------------------------------------------
// Bucket edges by dest AND materialize edge_attr in sorted order as bf16.
// edge_attr read is SEQUENTIAL (e), eb write is scattered 128B (full lines).
// This removes the random dependent edge_attr gather from the edge kernel.
// ---------------------------------------------------------------------------
__global__ void k_bucket(const int* __restrict__ ei, int* __restrict__ base,
                         int* __restrict__ srcrow, int* __restrict__ dstcol,
                         const float* __restrict__ ea,
                         unsigned short* __restrict__ eb, int E) {
    int i = blockIdx.x * blockDim.x + threadIdx.x;
    int stride = gridDim.x * blockDim.x;
    for (int e = i; e < E; e += stride) {
        int c = ei[E + e];
        int r = ei[e];
        int p = atomicAdd(&base[c], 1);       // consumes base (cursor)
        srcrow[p] = r;
        dstcol[p] = c;
        const float4* ar = (const float4*)(ea + (size_t)e * D_EDGE);
        uint4* ob = (uint4*)(eb + (size_t)p * D_EDGE);
        #pragma unroll
        for (int k = 0; k < 8; ++k) {
            float4 v0 = ar[2 * k];
            float4 v1 = ar[2 * k + 1];
            uint4 o;
            o.x = pk2(v0.x, v0.y); o.y = pk2(v0.z, v0.w);
            o.z = pk2(v1.x, v1.y); o.w = pk2(v1.z, v1.w);
            ob[k] = o;
        }
    }
}

// ---------------------------------------------------------------------------
// Edge kernel over DEST-SORTED edges, 64-edge tiles:
//   stage: xb row gather (L3-resident, index prefetched 1 tile ahead) +
//          eb SEQUENTIAL stream (8KB/tile, no index dependency)
//   -> MFMA y = h@W1+b1 -> LN -> LeakyReLU -> y^T (bf16, swizzled)
//   -> segmented sum via MFMA with selection matrix P^T.
// 256 threads = 4 waves; wave w owns cols [32w,32w+32); W1 frags in registers.
// ---------------------------------------------------------------------------
__global__ __launch_bounds__(256, 5) void edge_mfma_seg(
    const unsigned short* __restrict__ xb,
    const unsigned short* __restrict__ eb,
    const int*   __restrict__ srcrow,
    const int*   __restrict__ dstcol,
    const float* __restrict__ W1,
    const float* __restrict__ b1,
    const float* __restrict__ g1,
    const float* __restrict__ be1,
    float* __restrict__ sums,
    int E, int ntiles)
{
    __shared__ __align__(16) unsigned short h[64][200];   // 25600 B; reused for yT+PT
    __shared__ float rS [64][4], rS2[64][4];
    __shared__ int   scol[64];
    __shared__ int   rdest[64];
    __shared__ int   nruns_sh;

    unsigned short (*yT)[64] = (unsigned short (*)[64])(&h[0][0]);
    unsigned short (*PT)[64] = (unsigned short (*)[64])((char*)(&h[0][0]) + 16384);

    const int tid = threadIdx.x;
    const int w   = tid >> 6;
    const int l   = tid & 63;
    const int lm  = l & 15;
    const int q   = l >> 4;
    const int q8  = q * 8;
    const int e   = tid >> 2;
    const int qq  = tid & 3;

    // W1 fragments, bias/gamma/beta for this wave's 32 cols (once per block)
    bf16x8 Bfr[2][6];
    float  b1v[2], g1v[2], bev[2];
    #pragma unroll
    for (int c2 = 0; c2 < 2; ++c2) {
        const int n = (2 * w + c2) * 16 + lm;
        b1v[c2] = b1[n]; g1v[c2] = g1[n]; bev[c2] = be1[n];
        #pragma unroll
        for (int kt = 0; kt < 6; ++kt) {
            bf16x8 f;
            #pragma unroll
            for (int j = 0; j < 8; ++j)
                f[j] = (short)f2bf(W1[(kt * 32 + q8 + j) * 128 + n]);
            Bfr[c2][kt] = f;
        }
    }

    const int stride_t = gridDim.x;
    int tile = blockIdx.x;

    // index-only prefetch (2 VGPRs, no spill risk)
    int cur_row = (tile * 64 + e < E) ? srcrow[tile * 64 + e] : 0;
    int cur_sc  = (tid < 64 && tile * 64 + tid < E) ? dstcol[tile * 64 + tid] : -1;

    for (; tile < ntiles; tile += stride_t) {
        const int e0 = tile * 64;
        const int ge = e0 + e;

        // ---- stage h tile ----
        if (ge < E) {
            const uint4* xr = (const uint4*)(xb + (size_t)cur_row * D_NODE) + qq * 4;
            uint4 x0 = xr[0], x1 = xr[1], x2 = xr[2], x3 = xr[3];
            const uint4* ar = (const uint4*)(eb + (size_t)ge * D_EDGE + qq * 16);
            uint4 a0 = ar[0], a1 = ar[1];
            *(uint4*)&h[e][qq * 32 +  0] = x0;
            *(uint4*)&h[e][qq * 32 +  8] = x1;
            *(uint4*)&h[e][qq * 32 + 16] = x2;
            *(uint4*)&h[e][qq * 32 + 24] = x3;
            *(uint4*)&h[e][128 + qq * 16]     = a0;
            *(uint4*)&h[e][128 + qq * 16 + 8] = a1;
        } else {
            uint4 z = make_uint4(0u, 0u, 0u, 0u);
            *(uint4*)&h[e][qq * 32 +  0] = z;
            *(uint4*)&h[e][qq * 32 +  8] = z;
            *(uint4*)&h[e][qq * 32 + 16] = z;
            *(uint4*)&h[e][qq * 32 + 24] = z;
            *(uint4*)&h[e][128 + qq * 16]     = z;
            *(uint4*)&h[e][128 + qq * 16 + 8] = z;
        }
        if (tid < 64) scol[tid] = cur_sc;
        __syncthreads();                       // B1: h/scol ready

        // ---- prefetch NEXT tile's indices (cheap: 2 regs) ----
        {
            const int nt = tile + stride_t;
            cur_row = (nt < ntiles && nt * 64 + e < E) ? srcrow[nt * 64 + e] : 0;
            cur_sc  = (nt < ntiles && tid < 64 && nt * 64 + tid < E)
                        ? dstcol[nt * 64 + tid] : -1;
        }

        // ---- MFMA: 4 edge-tiles x 2 col-tiles, K=192 ----
        f32x4 acc[4][2];
        #pragma unroll
        for (int et = 0; et < 4; ++et)
            #pragma unroll
            for (int c2 = 0; c2 < 2; ++c2)
                acc[et][c2] = (f32x4){0.f, 0.f, 0.f, 0.f};

        #pragma unroll
        for (int et = 0; et < 4; ++et) {
            bf16x8 Afr[6];
            #pragma unroll
            for (int kt = 0; kt < 6; ++kt)
                Afr[kt] = *(const bf16x8*)&h[et * 16 + lm][kt * 32 + q8];
            #pragma unroll
            for (int c2 = 0; c2 < 2; ++c2)
                #pragma unroll
                for (int kt = 0; kt < 6; ++kt)
                    acc[et][c2] = __builtin_amdgcn_mfma_f32_16x16x32_bf16(
                        Afr[kt], Bfr[c2][kt], acc[et][c2], 0, 0, 0);
        }

        // ---- bias + LN partial sums ----
        #pragma unroll
        for (int et = 0; et < 4; ++et) {
            #pragma unroll
            for (int r = 0; r < 4; ++r) {
                float v0 = acc[et][0][r] + b1v[0];
                float v1 = acc[et][1][r] + b1v[1];
                acc[et][0][r] = v0;
                acc[et][1][r] = v1;
                float s  = v0 + v1;
                float s2 = v0 * v0 + v1 * v1;
                #pragma unroll
                for (int off = 1; off < 16; off <<= 1) {
                    s  += __shfl_xor(s,  off, 16);
                    s2 += __shfl_xor(s2, off, 16);
                }
                if (lm == 0) {
                    const int em = et * 16 + q * 4 + r;
                    rS [em][w] = s;
                    rS2[em][w] = s2;
                }
            }
        }
        __syncthreads();                       // B2: rS ready; ALL h reads done

        // ---- wave 0: run metadata + selection matrix P^T ----
        if (tid < 64) {
            uint4 z = make_uint4(0u, 0u, 0u, 0u);
            #pragma unroll
            for (int i = 0; i < 8; ++i)
                *(uint4*)&PT[tid][i * 8] = z;
            int me = scol[tid];
            int pv = (tid == 0) ? (me ^ 1) : scol[tid - 1];   // force start at 0
            unsigned long long m = __ballot(me != pv);
            int run = __popcll(m & ((2ull << tid) - 1)) - 1;  // run id of edge tid
            if (me != pv) rdest[run] = me;
            if (tid == 0) nruns_sh = (int)__popcll(m);
            int ep = (tid & 7) | ((((tid >> 3) ^ (run & 7)) & 7) << 3);
            PT[run][ep] = 0x3F80;
        }

        // ---- finalize LN + LeakyReLU, write y^T (bf16, swizzled) ----
        #pragma unroll
        for (int et = 0; et < 4; ++et) {
            float yv[2][4];
            #pragma unroll
            for (int r = 0; r < 4; ++r) {
                const int em = et * 16 + q * 4 + r;
                float4 p  = *(const float4*)&rS [em][0];
                float4 p2 = *(const float4*)&rS2[em][0];
                const float S    = (p.x  + p.y)  + (p.z  + p.w);
                const float S2   = (p2.x + p2.y) + (p2.z + p2.w);
                const float mu   = S * (1.f / 128.f);
                const float var  = S2 * (1.f / 128.f) - mu * mu;
                const float rstd = rsqrtf(var + LN_EPS);
                #pragma unroll
                for (int c2 = 0; c2 < 2; ++c2) {
                    float y = (acc[et][c2][r] - mu) * rstd * g1v[c2] + bev[c2];
                    y = (y > 0.f) ? y : NEG * y;
                    yv[c2][r] = y;
                }
            }
            #pragma unroll
            for (int c2 = 0; c2 < 2; ++c2) {
                const int col = (2 * w + c2) * 16 + lm;
                const int em0 = et * 16 + q * 4;
                const int ch  = ((em0 >> 3) ^ (col & 7)) & 7;
                uint2 o;
                o.x = pk2(yv[c2][0], yv[c2][1]);
                o.y = pk2(yv[c2][2], yv[c2][3]);
                *(uint2*)&yT[col][ch * 8 + (q & 1) * 4] = o;
            }
        }
        __syncthreads();                       // B3: yT + PT + metadata ready

        // ---- segmented reduce via MFMA: D^T[col][run] ----
        {
            bf16x8 afr[2][2];
            #pragma unroll
            for (int ct = 0; ct < 2; ++ct)
                #pragma unroll
                for (int kt = 0; kt < 2; ++kt) {
                    const int col = w * 32 + ct * 16 + lm;
                    const int ch  = ((kt * 4 + q) ^ (col & 7)) & 7;
                    afr[ct][kt] = *(const bf16x8*)&yT[col][ch * 8];
                }
            const int nr = nruns_sh;
            for (int rt = 0; rt * 16 < nr; ++rt) {
                bf16x8 bfr[2];
                #pragma unroll
                for (int kt = 0; kt < 2; ++kt) {
                    const int rr = rt * 16 + lm;
                    const int ch = ((kt * 4 + q) ^ (rr & 7)) & 7;
                    bfr[kt] = *(const bf16x8*)&PT[rr][ch * 8];
                }
                f32x4 o0 = (f32x4){0.f, 0.f, 0.f, 0.f};
                f32x4 o1 = (f32x4){0.f, 0.f, 0.f, 0.f};
                #pragma unroll
                for (int kt = 0; kt < 2; ++kt) {
                    o0 = __builtin_amdgcn_mfma_f32_16x16x32_bf16(
                        afr[0][kt], bfr[kt], o0, 0, 0, 0);
                    o1 = __builtin_amdgcn_mfma_f32_16x16x32_bf16(
                        afr[1][kt], bfr[kt], o1, 0, 0, 0);
                }
                const int run = rt * 16 + lm;     // C layout: n = lane&15
                if (run < nr) {
                    const int dest = rdest[run];
                    if (dest >= 0) {
                        const bool at = (run == 0) || (run == nr - 1);
                        float* p0 = &sums[(size_t)dest * D_NODE + w * 32 + q * 4];
                        if (at) {
                            #pragma unroll
                            for (int r = 0; r < 4; ++r) {
                                atomicAdd(&p0[r],      o0[r]);
                                atomicAdd(&p0[16 + r], o1[r]);
                            }
                        } else {
                            *(f32x4*)p0        = o0;
                            *(f32x4*)(p0 + 16) = o1;
                        }
                    }
                }
            }
        }
        __syncthreads();                       // B4: protect h/scol/meta for next tile
    }
}

// ---------------------------------------------------------------------------
// Node kernel (MFMA): m = sums/cnt -> y = m@W2+b2 -> LN -> LeakyReLU
//                     -> +x -> LeakyReLU -> out.  64-node tiles.
// ---------------------------------------------------------------------------
__global__ __launch_bounds__(256) void node_mfma(
    const float* __restrict__ sums,
    const int*   __restrict__ hist,
    const float* __restrict__ x,
    const float* __restrict__ W2,
    const float* __restrict__ b2,
    const float* __restrict__ g2,
    const float* __restrict__ be2,
    float* __restrict__ out,
    int N)
{
    __shared__ __align__(16) unsigned short h[64][136];     // 17.4 KB
    __shared__ float rS [64][4], rS2[64][4];

    const int tid = threadIdx.x;
    const int w   = tid >> 6;
    const int l   = tid & 63;
    const int lm  = l & 15;
    const int q   = l >> 4;
    const int q8  = q * 8;

    bf16x8 Bfr[2][4];
    float  b2v[2], g2v[2], bev[2];
    #pragma unroll
    for (int c2 = 0; c2 < 2; ++c2) {
        const int n = (2 * w + c2) * 16 + lm;
        b2v[c2] = b2[n]; g2v[c2] = g2[n]; bev[c2] = be2[n];
        #pragma unroll
        for (int kt = 0; kt < 4; ++kt) {
            bf16x8 f;
            #pragma unroll
            for (int j = 0; j < 8; ++j)
                f[j] = (short)f2bf(W2[(kt * 32 + q8 + j) * 128 + n]);
            Bfr[c2][kt] = f;
        }
    }

    const int n0 = blockIdx.x * 64;

    // stage m = sums/cnt (bf16)
    {
        const int e  = tid >> 2;
        const int qq = tid & 3;
        const int gn = n0 + e;
        if (gn < N) {
            const int cnt = hist[gn];
            const float sc = (cnt > 0) ? 1.f / (float)cnt : 0.f;
            const float4* sr = (const float4*)(sums + (size_t)gn * D_NODE);
            #pragma unroll
            for (int i = 0; i < 8; ++i) {
                float4 v = sr[qq * 8 + i];
                *(uint2*)&h[e][qq * 32 + i * 4] =
                    make_uint2(pk2(v.x * sc, v.y * sc), pk2(v.z * sc, v.w * sc));
            }
        } else {
            #pragma unroll
            for (int i = 0; i < 8; ++i)
                *(uint2*)&h[e][qq * 32 + i * 4] = make_uint2(0u, 0u);
        }
    }
    __syncthreads();

    f32x4 acc[4][2];
    #pragma unroll
    for (int et = 0; et < 4; ++et)
        #pragma unroll
        for (int c2 = 0; c2 < 2; ++c2)
            acc[et][c2] = (f32x4){0.f, 0.f, 0.f, 0.f};

    #pragma unroll
    for (int et = 0; et < 4; ++et) {
        bf16x8 Afr[4];
        #pragma unroll
        for (int kt = 0; kt < 4; ++kt)
            Afr[kt] = *(const bf16x8*)&h[et * 16 + lm][kt * 32 + q8];
        #pragma unroll
        for (int c2 = 0; c2 < 2; ++c2)
            #pragma unroll
            for (int kt = 0; kt < 4; ++kt)
                acc[et][c2] = __builtin_amdgcn_mfma_f32_16x16x32_bf16(
                    Afr[kt], Bfr[c2][kt], acc[et][c2], 0, 0, 0);
    }

    #pragma unroll
    for (int et = 0; et < 4; ++et) {
        #pragma unroll
        for (int r = 0; r < 4; ++r) {
            float v0 = acc[et][0][r] + b2v[0];
            float v1 = acc[et][1][r] + b2v[1];
            acc[et][0][r] = v0;
            acc[et][1][r] = v1;
            float s  = v0 + v1;
            float s2 = v0 * v0 + v1 * v1;
            #pragma unroll
            for (int off = 1; off < 16; off <<= 1) {
                s  += __shfl_xor(s,  off, 16);
                s2 += __shfl_xor(s2, off, 16);
            }
            if (lm == 0) {
                const int em = et * 16 + q * 4 + r;
                rS [em][w] = s;
                rS2[em][w] = s2;
            }
        }
    }
    __syncthreads();

    #pragma unroll
    for (int et = 0; et < 4; ++et) {
        #pragma unroll
        for (int r = 0; r < 4; ++r) {
            const int em = et * 16 + q * 4 + r;
            const int gn = n0 + em;
            if (gn >= N) continue;
            float4 p  = *(const float4*)&rS [em][0];
            float4 p2 = *(const float4*)&rS2[em][0];
            const float S    = (p.x  + p.y)  + (p.z  + p.w);
            const float S2   = (p2.x + p2.y) + (p2.z + p2.w);
            const float mu   = S * (1.f / 128.f);
            const float var  = S2 * (1.f / 128.f) - mu * mu;
            const float rstd = rsqrtf(var + LN_EPS);
            #pragma unroll
            for (int c2 = 0; c2 < 2; ++c2) {
                const int col = (2 * w + c2) * 16 + lm;
                float y = (acc[et][c2][r] - mu) * rstd * g2v[c2] + bev[c2];
                y = (y > 0.f) ? y : NEG * y;
                float rr = y + x[(size_t)gn * D_NODE + col];
                rr = (rr > 0.f) ? rr : NEG * rr;
                out[(size_t)gn * D_NODE + col] = rr;
            }
        }
    }
}

// ---------------------------------------------------------------------------
extern "C" void kernel_launch(void* const* d_in, const int* in_sizes, int n_in,
                              void* d_out, int out_size, void* d_ws, size_t ws_size,
                              hipStream_t stream) {
    const float* x          = (const float*)d_in[0];
    const int*   edge_index = (const int*)  d_in[1];
    const float* edge_attr  = (const float*)d_in[2];
    const float* W1         = (const float*)d_in[3];
    const float* b1         = (const float*)d_in[4];
    const float* g1         = (const float*)d_in[5];
    const float* be1        = (const float*)d_in[6];
    const float* W2         = (const float*)d_in[7];
    const float* b2         = (const float*)d_in[8];
    const float* g2         = (const float*)d_in[9];
    const float* be2        = (const float*)d_in[10];

    const int N = in_sizes[0] / D_NODE;     // 50000
    const int E = in_sizes[1] / 2;          // 600000

    float* sums     = (float*)d_ws;                        // N*128 f32
    int*   hist     = (int*)(sums + (size_t)N * D_NODE);   // N
    int*   base     = hist + N;                            // N
    int*   blockTot = base + N;                            // 64
    int*   srcrow   = blockTot + 64;                       // E
    int*   dstcol   = srcrow + E;                          // E
    unsigned short* xb = (unsigned short*)(dstcol + E);    // N*128 bf16
    unsigned short* eb = xb + (size_t)N * D_NODE;          // E*64 bf16 (~120 MB total)

    // zero sums + hist in one shot
    hipMemsetAsync(d_ws, 0, ((size_t)N * D_NODE + (size_t)N) * sizeof(float), stream);

    const int n8 = N * (D_NODE / 8);
    k_packx<<<dim3(1024), dim3(256), 0, stream>>>(x, xb, n8);

    k_hist<<<dim3(256), dim3(256), 0, stream>>>(edge_index, hist, E);
    const int NB = (N + 1023) / 1024;                      // 49 (<=64)
    k_scanA<<<dim3(NB), dim3(1024), 0, stream>>>(hist, base, blockTot, N);
    k_scanB<<<dim3(1),  dim3(64),   0, stream>>>(blockTot, NB);
    k_scanC<<<dim3(NB), dim3(1024), 0, stream>>>(base, blockTot, N);
    k_bucket<<<dim3(1024), dim3(256), 0, stream>>>(edge_index, base, srcrow, dstcol,
                                                   edge_attr, eb, E);

    const int ntiles = (E + 63) / 64;
    const int grid   = ntiles < 1280 ? ntiles : 1280;      // 5 blocks/CU (LDS-limited)
    edge_mfma_seg<<<dim3(grid), dim3(256), 0, stream>>>(
        xb, eb, srcrow, dstcol, W1, b1, g1, be1, sums, E, ntiles);

    node_mfma<<<dim3((N + 63) / 64), dim3(256), 0, stream>>>(
        sums, hist, x, W2, b2, g2, be2, (float*)d_out, N);
}

// Round 4
// 491.133 us; speedup vs baseline: 1.4910x; 1.2957x over previous
//
#include <hip/hip_runtime.h>

#define D_NODE 128
#define D_EDGE 64
#define D_IN   192
#define NEG    0.01f
#define LN_EPS 1e-5f

typedef short bf16x8 __attribute__((ext_vector_type(8)));
typedef float f32x4  __attribute__((ext_vector_type(4)));

__device__ __forceinline__ unsigned f2bf(float f) {
    unsigned u = __builtin_bit_cast(unsigned, f);
    return (u + 0x7FFFu + ((u >> 16) & 1u)) >> 16;   // RNE
}
__device__ __forceinline__ unsigned pk2(float a, float b) {
    return f2bf(a) | (f2bf(b) << 16);
}

// ---------------------------------------------------------------------------
// Pre-pack x (N x 128 f32) -> bf16 once (halves x-gather prefetch registers).
// ---------------------------------------------------------------------------
__global__ void k_packx(const float* __restrict__ x, unsigned short* __restrict__ xb,
                        int n8) {
    int i = blockIdx.x * blockDim.x + threadIdx.x;
    int stride = gridDim.x * blockDim.x;
    for (int t = i; t < n8; t += stride) {
        const float4* p = (const float4*)x + (size_t)t * 2;
        float4 a = p[0], b = p[1];
        uint4 o;
        o.x = pk2(a.x, a.y); o.y = pk2(a.z, a.w);
        o.z = pk2(b.x, b.y); o.w = pk2(b.z, b.w);
        ((uint4*)xb)[t] = o;
    }
}

// ---------------------------------------------------------------------------
// Counting sort of edges by destination: hist -> exclusive scan -> bucket.
// ---------------------------------------------------------------------------
__global__ void k_hist(const int* __restrict__ ei, int* __restrict__ hist, int E) {
    int i = blockIdx.x * blockDim.x + threadIdx.x;
    int stride = gridDim.x * blockDim.x;
    for (int e = i; e < E; e += stride) atomicAdd(&hist[ei[E + e]], 1);
}

__global__ __launch_bounds__(1024) void k_scanA(const int* __restrict__ hist,
                                                int* __restrict__ base,
                                                int* __restrict__ blockTot, int N) {
    __shared__ int wsum[16], woff[16];
    const int t = threadIdx.x, b = blockIdx.x;
    const int i = b * 1024 + t;
    const int lane = t & 63, w = t >> 6;
    int v = (i < N) ? hist[i] : 0;
    int x = v;
    #pragma unroll
    for (int d = 1; d < 64; d <<= 1) { int u = __shfl_up(x, d); if (lane >= d) x += u; }
    if (lane == 63) wsum[w] = x;
    __syncthreads();
    if (t < 16) {
        int y = wsum[t];
        #pragma unroll
        for (int d = 1; d < 16; d <<= 1) { int u = __shfl_up(y, d, 16); if (t >= d) y += u; }
        woff[t] = y - wsum[t];
    }
    __syncthreads();
    int incl = x + woff[w];
    if (i < N) base[i] = incl - v;            // exclusive within block
    if (t == 1023) blockTot[b] = incl;
}

__global__ void k_scanB(int* __restrict__ blockTot, int NB) {   // 1 block, 64 thr, NB<=64
    int t = threadIdx.x;
    int v = (t < NB) ? blockTot[t] : 0;
    int x = v;
    #pragma unroll
    for (int d = 1; d < 64; d <<= 1) { int u = __shfl_up(x, d); if (t >= d) x += u; }
    if (t < NB) blockTot[t] = x - v;          // exclusive block offsets
}

__global__ __launch_bounds__(1024) void k_scanC(int* __restrict__ base,
                                                const int* __restrict__ blockTot, int N) {
    int i = blockIdx.x * 1024 + threadIdx.x;
    if (i < N) base[i] += blockTot[blockIdx.x];
}

__global__ void k_bucket(const int* __restrict__ ei, int* __restrict__ base,
                         int* __restrict__ perm, int* __restrict__ srcrow,
                         int* __restrict__ dstcol, int E) {
    int i = blockIdx.x * blockDim.x + threadIdx.x;
    int stride = gridDim.x * blockDim.x;
    for (int e = i; e < E; e += stride) {
        int c = ei[E + e];
        int r = ei[e];
        int p = atomicAdd(&base[c], 1);       // consumes base (cursor)
        perm[p]   = e;
        srcrow[p] = r;
        dstcol[p] = c;
    }
}

// ---------------------------------------------------------------------------
// Edge kernel over DEST-SORTED edges, 64-edge tiles, SOFTWARE-PIPELINED:
//   tile t+1's gathers (xb rows, edge_attr rows, dstcol) are issued into
//   REGISTERS right after B1 of tile t; the ~500-900cy gather latency hides
//   under MFMA + LN + MFMA-reduce of tile t.
//   NOTE: plain __launch_bounds__(256) — round 2 showed a min-waves hint
//   pins VGPR=64 and spills the prefetch regs (WRITE_SIZE +272MB).
//   ~90-110 VGPR -> 16 waves/CU (4 blocks), grid = 1024.
// ---------------------------------------------------------------------------
__global__ __launch_bounds__(256) void edge_mfma_seg(
    const unsigned short* __restrict__ xb,
    const float* __restrict__ edge_attr,
    const int*   __restrict__ perm,
    const int*   __restrict__ srcrow,
    const int*   __restrict__ dstcol,
    const float* __restrict__ W1,
    const float* __restrict__ b1,
    const float* __restrict__ g1,
    const float* __restrict__ be1,
    float* __restrict__ sums,
    int E, int ntiles)
{
    __shared__ __align__(16) unsigned short h[64][200];   // 25600 B; reused for yT+PT
    __shared__ float rS [64][4], rS2[64][4];
    __shared__ int   scol[64];
    __shared__ int   rdest[64];
    __shared__ int   nruns_sh;

    unsigned short (*yT)[64] = (unsigned short (*)[64])(&h[0][0]);
    unsigned short (*PT)[64] = (unsigned short (*)[64])((char*)(&h[0][0]) + 16384);

    const int tid = threadIdx.x;
    const int w   = tid >> 6;
    const int l   = tid & 63;
    const int lm  = l & 15;
    const int q   = l >> 4;
    const int q8  = q * 8;
    const int e   = tid >> 2;
    const int qq  = tid & 3;

    // W1 fragments, bias/gamma/beta for this wave's 32 cols (once per block)
    bf16x8 Bfr[2][6];
    float  b1v[2], g1v[2], bev[2];
    #pragma unroll
    for (int c2 = 0; c2 < 2; ++c2) {
        const int n = (2 * w + c2) * 16 + lm;
        b1v[c2] = b1[n]; g1v[c2] = g1[n]; bev[c2] = be1[n];
        #pragma unroll
        for (int kt = 0; kt < 6; ++kt) {
            bf16x8 f;
            #pragma unroll
            for (int j = 0; j < 8; ++j)
                f[j] = (short)f2bf(W1[(kt * 32 + q8 + j) * 128 + n]);
            Bfr[c2][kt] = f;
        }
    }

    const int stride_t = gridDim.x;
    int tile = blockIdx.x;                    // < ntiles (grid is clamped)

    // ---- prologue: stage tile `tile` into registers ----
    uint4  xr0, xr1, xr2, xr3;                // 16 VGPR: x row (bf16)
    float4 af0, af1, af2, af3;                // 16 VGPR: edge_attr row (f32)
    int    sc;
    bool   vld;
    {
        const int ge = tile * 64 + e;
        vld = (ge < E);
        if (vld) {
            const int row = srcrow[ge];
            const int eid = perm[ge];
            const uint4* xr = (const uint4*)(xb + (size_t)row * D_NODE) + qq * 4;
            xr0 = xr[0]; xr1 = xr[1]; xr2 = xr[2]; xr3 = xr[3];
            const float4* ar = (const float4*)(edge_attr + (size_t)eid * D_EDGE) + qq * 4;
            af0 = ar[0]; af1 = ar[1]; af2 = ar[2]; af3 = ar[3];
        }
        sc = (tid < 64 && tile * 64 + tid < E) ? dstcol[tile * 64 + tid] : -1;
    }

    for (; tile < ntiles; tile += stride_t) {
        // ---- staged regs -> LDS (vmcnt wait for prefetch lands here) ----
        if (vld) {
            *(uint4*)&h[e][qq * 32 +  0] = xr0;
            *(uint4*)&h[e][qq * 32 +  8] = xr1;
            *(uint4*)&h[e][qq * 32 + 16] = xr2;
            *(uint4*)&h[e][qq * 32 + 24] = xr3;
            uint4 o;
            o.x = pk2(af0.x, af0.y); o.y = pk2(af0.z, af0.w);
            o.z = pk2(af1.x, af1.y); o.w = pk2(af1.z, af1.w);
            *(uint4*)&h[e][128 + qq * 16] = o;
            o.x = pk2(af2.x, af2.y); o.y = pk2(af2.z, af2.w);
            o.z = pk2(af3.x, af3.y); o.w = pk2(af3.z, af3.w);
            *(uint4*)&h[e][128 + qq * 16 + 8] = o;
        } else {
            uint4 z = make_uint4(0u, 0u, 0u, 0u);
            *(uint4*)&h[e][qq * 32 +  0] = z;
            *(uint4*)&h[e][qq * 32 +  8] = z;
            *(uint4*)&h[e][qq * 32 + 16] = z;
            *(uint4*)&h[e][qq * 32 + 24] = z;
            *(uint4*)&h[e][128 + qq * 16]     = z;
            *(uint4*)&h[e][128 + qq * 16 + 8] = z;
        }
        if (tid < 64) scol[tid] = sc;
        __syncthreads();                       // B1: h/scol ready

        // ---- issue NEXT tile's gathers into registers (hide under compute) ----
        {
            const int nt = tile + stride_t;
            const int ge = nt * 64 + e;
            vld = (nt < ntiles) && (ge < E);
            if (vld) {
                const int row = srcrow[ge];
                const int eid = perm[ge];
                const uint4* xr = (const uint4*)(xb + (size_t)row * D_NODE) + qq * 4;
                xr0 = xr[0]; xr1 = xr[1]; xr2 = xr[2]; xr3 = xr[3];
                const float4* ar = (const float4*)(edge_attr + (size_t)eid * D_EDGE) + qq * 4;
                af0 = ar[0]; af1 = ar[1]; af2 = ar[2]; af3 = ar[3];
            }
            sc = (nt < ntiles && tid < 64 && nt * 64 + tid < E)
                   ? dstcol[nt * 64 + tid] : -1;
        }

        // ---- MFMA: 4 edge-tiles x 2 col-tiles, K=192 ----
        f32x4 acc[4][2];
        #pragma unroll
        for (int et = 0; et < 4; ++et)
            #pragma unroll
            for (int c2 = 0; c2 < 2; ++c2)
                acc[et][c2] = (f32x4){0.f, 0.f, 0.f, 0.f};

        #pragma unroll
        for (int et = 0; et < 4; ++et) {
            bf16x8 Afr[6];
            #pragma unroll
            for (int kt = 0; kt < 6; ++kt)
                Afr[kt] = *(const bf16x8*)&h[et * 16 + lm][kt * 32 + q8];
            #pragma unroll
            for (int c2 = 0; c2 < 2; ++c2)
                #pragma unroll
                for (int kt = 0; kt < 6; ++kt)
                    acc[et][c2] = __builtin_amdgcn_mfma_f32_16x16x32_bf16(
                        Afr[kt], Bfr[c2][kt], acc[et][c2], 0, 0, 0);
        }

        // ---- bias + LN partial sums ----
        #pragma unroll
        for (int et = 0; et < 4; ++et) {
            #pragma unroll
            for (int r = 0; r < 4; ++r) {
                float v0 = acc[et][0][r] + b1v[0];
                float v1 = acc[et][1][r] + b1v[1];
                acc[et][0][r] = v0;
                acc[et][1][r] = v1;
                float s  = v0 + v1;
                float s2 = v0 * v0 + v1 * v1;
                #pragma unroll
                for (int off = 1; off < 16; off <<= 1) {
                    s  += __shfl_xor(s,  off, 16);
                    s2 += __shfl_xor(s2, off, 16);
                }
                if (lm == 0) {
                    const int em = et * 16 + q * 4 + r;
                    rS [em][w] = s;
                    rS2[em][w] = s2;
                }
            }
        }
        __syncthreads();                       // B2: rS ready; ALL h reads done

        // ---- wave 0: run metadata + selection matrix P^T ----
        if (tid < 64) {
            uint4 z = make_uint4(0u, 0u, 0u, 0u);
            #pragma unroll
            for (int i = 0; i < 8; ++i)
                *(uint4*)&PT[tid][i * 8] = z;
            int me = scol[tid];
            int pv = (tid == 0) ? (me ^ 1) : scol[tid - 1];   // force start at 0
            unsigned long long m = __ballot(me != pv);
            int run = __popcll(m & ((2ull << tid) - 1)) - 1;  // run id of edge tid
            if (me != pv) rdest[run] = me;
            if (tid == 0) nruns_sh = (int)__popcll(m);
            int ep = (tid & 7) | ((((tid >> 3) ^ (run & 7)) & 7) << 3);
            PT[run][ep] = 0x3F80;
        }

        // ---- finalize LN + LeakyReLU, write y^T (bf16, swizzled) ----
        #pragma unroll
        for (int et = 0; et < 4; ++et) {
            float yv[2][4];
            #pragma unroll
            for (int r = 0; r < 4; ++r) {
                const int em = et * 16 + q * 4 + r;
                float4 p  = *(const float4*)&rS [em][0];
                float4 p2 = *(const float4*)&rS2[em][0];
                const float S    = (p.x  + p.y)  + (p.z  + p.w);
                const float S2   = (p2.x + p2.y) + (p2.z + p2.w);
                const float mu   = S * (1.f / 128.f);
                const float var  = S2 * (1.f / 128.f) - mu * mu;
                const float rstd = rsqrtf(var + LN_EPS);
                #pragma unroll
                for (int c2 = 0; c2 < 2; ++c2) {
                    float y = (acc[et][c2][r] - mu) * rstd * g1v[c2] + bev[c2];
                    y = (y > 0.f) ? y : NEG * y;
                    yv[c2][r] = y;
                }
            }
            #pragma unroll
            for (int c2 = 0; c2 < 2; ++c2) {
                const int col = (2 * w + c2) * 16 + lm;
                const int em0 = et * 16 + q * 4;
                const int ch  = ((em0 >> 3) ^ (col & 7)) & 7;
                uint2 o;
                o.x = pk2(yv[c2][0], yv[c2][1]);
                o.y = pk2(yv[c2][2], yv[c2][3]);
                *(uint2*)&yT[col][ch * 8 + (q & 1) * 4] = o;
            }
        }
        __syncthreads();                       // B3: yT + PT + metadata ready

        // ---- segmented reduce via MFMA: D^T[col][run] ----
        {
            bf16x8 afr[2][2];
            #pragma unroll
            for (int ct = 0; ct < 2; ++ct)
                #pragma unroll
                for (int kt = 0; kt < 2; ++kt) {
                    const int col = w * 32 + ct * 16 + lm;
                    const int ch  = ((kt * 4 + q) ^ (col & 7)) & 7;
                    afr[ct][kt] = *(const bf16x8*)&yT[col][ch * 8];
                }
            const int nr = nruns_sh;
            for (int rt = 0; rt * 16 < nr; ++rt) {
                bf16x8 bfr[2];
                #pragma unroll
                for (int kt = 0; kt < 2; ++kt) {
                    const int rr = rt * 16 + lm;
                    const int ch = ((kt * 4 + q) ^ (rr & 7)) & 7;
                    bfr[kt] = *(const bf16x8*)&PT[rr][ch * 8];
                }
                f32x4 o0 = (f32x4){0.f, 0.f, 0.f, 0.f};
                f32x4 o1 = (f32x4){0.f, 0.f, 0.f, 0.f};
                #pragma unroll
                for (int kt = 0; kt < 2; ++kt) {
                    o0 = __builtin_amdgcn_mfma_f32_16x16x32_bf16(
                        afr[0][kt], bfr[kt], o0, 0, 0, 0);
                    o1 = __builtin_amdgcn_mfma_f32_16x16x32_bf16(
                        afr[1][kt], bfr[kt], o1, 0, 0, 0);
                }
                const int run = rt * 16 + lm;     // C layout: n = lane&15
                if (run < nr) {
                    const int dest = rdest[run];
                    if (dest >= 0) {
                        const bool at = (run == 0) || (run == nr - 1);
                        float* p0 = &sums[(size_t)dest * D_NODE + w * 32 + q * 4];
                        if (at) {
                            #pragma unroll
                            for (int r = 0; r < 4; ++r) {
                                atomicAdd(&p0[r],      o0[r]);
                                atomicAdd(&p0[16 + r], o1[r]);
                            }
                        } else {
                            *(f32x4*)p0        = o0;
                            *(f32x4*)(p0 + 16) = o1;
                        }
                    }
                }
            }
        }
        __syncthreads();                       // B4: protect h/scol/meta for next tile
    }
}

// ---------------------------------------------------------------------------
// Node kernel (MFMA): m = sums/cnt -> y = m@W2+b2 -> LN -> LeakyReLU
//                     -> +x -> LeakyReLU -> out.  64-node tiles.
// ---------------------------------------------------------------------------
__global__ __launch_bounds__(256) void node_mfma(
    const float* __restrict__ sums,
    const int*   __restrict__ hist,
    const float* __restrict__ x,
    const float* __restrict__ W2,
    const float* __restrict__ b2,
    const float* __restrict__ g2,
    const float* __restrict__ be2,
    float* __restrict__ out,
    int N)
{
    __shared__ __align__(16) unsigned short h[64][136];     // 17.4 KB
    __shared__ float rS [64][4], rS2[64][4];

    const int tid = threadIdx.x;
    const int w   = tid >> 6;
    const int l   = tid & 63;
    const int lm  = l & 15;
    const int q   = l >> 4;
    const int q8  = q * 8;

    bf16x8 Bfr[2][4];
    float  b2v[2], g2v[2], bev[2];
    #pragma unroll
    for (int c2 = 0; c2 < 2; ++c2) {
        const int n = (2 * w + c2) * 16 + lm;
        b2v[c2] = b2[n]; g2v[c2] = g2[n]; bev[c2] = be2[n];
        #pragma unroll
        for (int kt = 0; kt < 4; ++kt) {
            bf16x8 f;
            #pragma unroll
            for (int j = 0; j < 8; ++j)
                f[j] = (short)f2bf(W2[(kt * 32 + q8 + j) * 128 + n]);
            Bfr[c2][kt] = f;
        }
    }

    const int n0 = blockIdx.x * 64;

    // stage m = sums/cnt (bf16)
    {
        const int e  = tid >> 2;
        const int qq = tid & 3;
        const int gn = n0 + e;
        if (gn < N) {
            const int cnt = hist[gn];
            const float sc = (cnt > 0) ? 1.f / (float)cnt : 0.f;
            const float4* sr = (const float4*)(sums + (size_t)gn * D_NODE);
            #pragma unroll
            for (int i = 0; i < 8; ++i) {
                float4 v = sr[qq * 8 + i];
                *(uint2*)&h[e][qq * 32 + i * 4] =
                    make_uint2(pk2(v.x * sc, v.y * sc), pk2(v.z * sc, v.w * sc));
            }
        } else {
            #pragma unroll
            for (int i = 0; i < 8; ++i)
                *(uint2*)&h[e][qq * 32 + i * 4] = make_uint2(0u, 0u);
        }
    }
    __syncthreads();

    f32x4 acc[4][2];
    #pragma unroll
    for (int et = 0; et < 4; ++et)
        #pragma unroll
        for (int c2 = 0; c2 < 2; ++c2)
            acc[et][c2] = (f32x4){0.f, 0.f, 0.f, 0.f};

    #pragma unroll
    for (int et = 0; et < 4; ++et) {
        bf16x8 Afr[4];
        #pragma unroll
        for (int kt = 0; kt < 4; ++kt)
            Afr[kt] = *(const bf16x8*)&h[et * 16 + lm][kt * 32 + q8];
        #pragma unroll
        for (int c2 = 0; c2 < 2; ++c2)
            #pragma unroll
            for (int kt = 0; kt < 4; ++kt)
                acc[et][c2] = __builtin_amdgcn_mfma_f32_16x16x32_bf16(
                    Afr[kt], Bfr[c2][kt], acc[et][c2], 0, 0, 0);
    }

    #pragma unroll
    for (int et = 0; et < 4; ++et) {
        #pragma unroll
        for (int r = 0; r < 4; ++r) {
            float v0 = acc[et][0][r] + b2v[0];
            float v1 = acc[et][1][r] + b2v[1];
            acc[et][0][r] = v0;
            acc[et][1][r] = v1;
            float s  = v0 + v1;
            float s2 = v0 * v0 + v1 * v1;
            #pragma unroll
            for (int off = 1; off < 16; off <<= 1) {
                s  += __shfl_xor(s,  off, 16);
                s2 += __shfl_xor(s2, off, 16);
            }
            if (lm == 0) {
                const int em = et * 16 + q * 4 + r;
                rS [em][w] = s;
                rS2[em][w] = s2;
            }
        }
    }
    __syncthreads();

    #pragma unroll
    for (int et = 0; et < 4; ++et) {
        #pragma unroll
        for (int r = 0; r < 4; ++r) {
            const int em = et * 16 + q * 4 + r;
            const int gn = n0 + em;
            if (gn >= N) continue;
            float4 p  = *(const float4*)&rS [em][0];
            float4 p2 = *(const float4*)&rS2[em][0];
            const float S    = (p.x  + p.y)  + (p.z  + p.w);
            const float S2   = (p2.x + p2.y) + (p2.z + p2.w);
            const float mu   = S * (1.f / 128.f);
            const float var  = S2 * (1.f / 128.f) - mu * mu;
            const float rstd = rsqrtf(var + LN_EPS);
            #pragma unroll
            for (int c2 = 0; c2 < 2; ++c2) {
                const int col = (2 * w + c2) * 16 + lm;
                float y = (acc[et][c2][r] - mu) * rstd * g2v[c2] + bev[c2];
                y = (y > 0.f) ? y : NEG * y;
                float rr = y + x[(size_t)gn * D_NODE + col];
                rr = (rr > 0.f) ? rr : NEG * rr;
                out[(size_t)gn * D_NODE + col] = rr;
            }
        }
    }
}

// ---------------------------------------------------------------------------
extern "C" void kernel_launch(void* const* d_in, const int* in_sizes, int n_in,
                              void* d_out, int out_size, void* d_ws, size_t ws_size,
                              hipStream_t stream) {
    const float* x          = (const float*)d_in[0];
    const int*   edge_index = (const int*)  d_in[1];
    const float* edge_attr  = (const float*)d_in[2];
    const float* W1         = (const float*)d_in[3];
    const float* b1         = (const float*)d_in[4];
    const float* g1         = (const float*)d_in[5];
    const float* be1        = (const float*)d_in[6];
    const float* W2         = (const float*)d_in[7];
    const float* b2         = (const float*)d_in[8];
    const float* g2         = (const float*)d_in[9];
    const float* be2        = (const float*)d_in[10];

    const int N = in_sizes[0] / D_NODE;     // 50000
    const int E = in_sizes[1] / 2;          // 600000

    float* sums     = (float*)d_ws;                        // N*128 f32
    int*   hist     = (int*)(sums + (size_t)N * D_NODE);   // N
    int*   base     = hist + N;                            // N
    int*   blockTot = base + N;                            // 64
    int*   perm     = blockTot + 64;                       // E
    int*   srcrow   = perm + E;                            // E
    int*   dstcol   = srcrow + E;                          // E
    unsigned short* xb = (unsigned short*)(dstcol + E);    // N*128 bf16 (~46 MB total)

    // zero sums + hist in one shot
    hipMemsetAsync(d_ws, 0, ((size_t)N * D_NODE + (size_t)N) * sizeof(float), stream);

    const int n8 = N * (D_NODE / 8);
    k_packx<<<dim3(1024), dim3(256), 0, stream>>>(x, xb, n8);

    k_hist<<<dim3(256), dim3(256), 0, stream>>>(edge_index, hist, E);
    const int NB = (N + 1023) / 1024;                      // 49 (<=64)
    k_scanA<<<dim3(NB), dim3(1024), 0, stream>>>(hist, base, blockTot, N);
    k_scanB<<<dim3(1),  dim3(64),   0, stream>>>(blockTot, NB);
    k_scanC<<<dim3(NB), dim3(1024), 0, stream>>>(base, blockTot, N);
    k_bucket<<<dim3(256), dim3(256), 0, stream>>>(edge_index, base, perm, srcrow, dstcol, E);

    const int ntiles = (E + 63) / 64;
    const int grid   = ntiles < 1024 ? ntiles : 1024;      // 4 blocks/CU (16 waves, VGPR<=128)
    edge_mfma_seg<<<dim3(grid), dim3(256), 0, stream>>>(
        xb, edge_attr, perm, srcrow, dstcol, W1, b1, g1, be1, sums, E, ntiles);

    node_mfma<<<dim3((N + 63) / 64), dim3(256), 0, stream>>>(
        sums, hist, x, W2, b2, g2, be2, (float*)d_out, N);
}

// Round 5
// 486.881 us; speedup vs baseline: 1.5040x; 1.0087x over previous
//
#include <hip/hip_runtime.h>

#define D_NODE 128
#define D_EDGE 64
#define D_IN   192
#define NEG    0.01f
#define LN_EPS 1e-5f

typedef short bf16x8 __attribute__((ext_vector_type(8)));
typedef float f32x4  __attribute__((ext_vector_type(4)));

__device__ __forceinline__ unsigned f2bf(float f) {
    unsigned u = __builtin_bit_cast(unsigned, f);
    return (u + 0x7FFFu + ((u >> 16) & 1u)) >> 16;   // RNE
}
__device__ __forceinline__ unsigned pk2(float a, float b) {
    return f2bf(a) | (f2bf(b) << 16);
}

// ---------------------------------------------------------------------------
// Pre-pack x (N x 128 f32) -> bf16 once (halves x-gather prefetch registers).
// ---------------------------------------------------------------------------
__global__ void k_packx(const float* __restrict__ x, unsigned short* __restrict__ xb,
                        int n8) {
    int i = blockIdx.x * blockDim.x + threadIdx.x;
    int stride = gridDim.x * blockDim.x;
    for (int t = i; t < n8; t += stride) {
        const float4* p = (const float4*)x + (size_t)t * 2;
        float4 a = p[0], b = p[1];
        uint4 o;
        o.x = pk2(a.x, a.y); o.y = pk2(a.z, a.w);
        o.z = pk2(b.x, b.y); o.w = pk2(b.z, b.w);
        ((uint4*)xb)[t] = o;
    }
}

// ---------------------------------------------------------------------------
// Counting sort of edges by destination: hist -> exclusive scan -> bucket.
// ---------------------------------------------------------------------------
__global__ void k_hist(const int* __restrict__ ei, int* __restrict__ hist, int E) {
    int i = blockIdx.x * blockDim.x + threadIdx.x;
    int stride = gridDim.x * blockDim.x;
    for (int e = i; e < E; e += stride) atomicAdd(&hist[ei[E + e]], 1);
}

__global__ __launch_bounds__(1024) void k_scanA(const int* __restrict__ hist,
                                                int* __restrict__ base,
                                                int* __restrict__ blockTot, int N) {
    __shared__ int wsum[16], woff[16];
    const int t = threadIdx.x, b = blockIdx.x;
    const int i = b * 1024 + t;
    const int lane = t & 63, w = t >> 6;
    int v = (i < N) ? hist[i] : 0;
    int x = v;
    #pragma unroll
    for (int d = 1; d < 64; d <<= 1) { int u = __shfl_up(x, d); if (lane >= d) x += u; }
    if (lane == 63) wsum[w] = x;
    __syncthreads();
    if (t < 16) {
        int y = wsum[t];
        #pragma unroll
        for (int d = 1; d < 16; d <<= 1) { int u = __shfl_up(y, d, 16); if (t >= d) y += u; }
        woff[t] = y - wsum[t];
    }
    __syncthreads();
    int incl = x + woff[w];
    if (i < N) base[i] = incl - v;            // exclusive within block
    if (t == 1023) blockTot[b] = incl;
}

__global__ void k_scanB(int* __restrict__ blockTot, int NB) {   // 1 block, 64 thr, NB<=64
    int t = threadIdx.x;
    int v = (t < NB) ? blockTot[t] : 0;
    int x = v;
    #pragma unroll
    for (int d = 1; d < 64; d <<= 1) { int u = __shfl_up(x, d); if (t >= d) x += u; }
    if (t < NB) blockTot[t] = x - v;          // exclusive block offsets
}

__global__ __launch_bounds__(1024) void k_scanC(int* __restrict__ base,
                                                const int* __restrict__ blockTot, int N) {
    int i = blockIdx.x * 1024 + threadIdx.x;
    if (i < N) base[i] += blockTot[blockIdx.x];
}

__global__ void k_bucket(const int* __restrict__ ei, int* __restrict__ base,
                         int* __restrict__ perm, int* __restrict__ srcrow,
                         int* __restrict__ dstcol, int E) {
    int i = blockIdx.x * blockDim.x + threadIdx.x;
    int stride = gridDim.x * blockDim.x;
    for (int e = i; e < E; e += stride) {
        int c = ei[E + e];
        int r = ei[e];
        int p = atomicAdd(&base[c], 1);       // consumes base (cursor)
        perm[p]   = e;
        srcrow[p] = r;
        dstcol[p] = c;
    }
}

// ---------------------------------------------------------------------------
// Edge kernel, 2-BARRIER pipeline (was 4):
//   B1: staged h + scol visible.  B2: rS (LN partials) visible + h consumed.
//   After B2 everything is WAVE-LOCAL: yT is a per-wave buffer aliased onto
//   the wave's own (dead) h rows; the P^T fragments for the segmented-reduce
//   MFMA are built IN REGISTERS from a per-wave recomputed ballot mask;
//   rdest is built redundantly by every wave.  scol is parity-double-buffered
//   to close the only cross-tile race.  Register prefetch of next tile's
//   gathers (round-4 win) is kept.
// ---------------------------------------------------------------------------
__global__ __launch_bounds__(256) void edge_mfma_seg(
    const unsigned short* __restrict__ xb,
    const float* __restrict__ edge_attr,
    const int*   __restrict__ perm,
    const int*   __restrict__ srcrow,
    const int*   __restrict__ dstcol,
    const float* __restrict__ W1,
    const float* __restrict__ b1,
    const float* __restrict__ g1,
    const float* __restrict__ be1,
    float* __restrict__ sums,
    int E, int ntiles)
{
    __shared__ __align__(16) unsigned short h[64][200];   // 25.6 KB
    __shared__ float rS [64][4], rS2[64][4];
    __shared__ int   scol2[2][64];
    __shared__ int   rdest[64];

    const int tid = threadIdx.x;
    const int w   = tid >> 6;
    const int l   = tid & 63;
    const int lm  = l & 15;
    const int q   = l >> 4;
    const int q8  = q * 8;
    const int e   = tid >> 2;                 // = 16w + (l>>2): wave-aligned rows
    const int qq  = tid & 3;

    // per-wave yT region: 32 cols x 64 edges bf16 (4KB), aliased onto the
    // wave's own h rows [16w,16w+16) (6.4KB) — dead after B2.
    unsigned short (*yT)[64] = (unsigned short (*)[64])(&h[w * 16][0]);

    // W1 fragments, bias/gamma/beta for this wave's 32 cols (once per block)
    bf16x8 Bfr[2][6];
    float  b1v[2], g1v[2], bev[2];
    #pragma unroll
    for (int c2 = 0; c2 < 2; ++c2) {
        const int n = (2 * w + c2) * 16 + lm;
        b1v[c2] = b1[n]; g1v[c2] = g1[n]; bev[c2] = be1[n];
        #pragma unroll
        for (int kt = 0; kt < 6; ++kt) {
            bf16x8 f;
            #pragma unroll
            for (int j = 0; j < 8; ++j)
                f[j] = (short)f2bf(W1[(kt * 32 + q8 + j) * 128 + n]);
            Bfr[c2][kt] = f;
        }
    }

    const int stride_t = gridDim.x;
    int tile = blockIdx.x;                    // < ntiles (grid is clamped)
    int pp   = 0;                             // scol parity

    // ---- prologue: stage tile `tile` into registers ----
    uint4  xr0, xr1, xr2, xr3;                // 16 VGPR: x row (bf16)
    float4 af0, af1, af2, af3;                // 16 VGPR: edge_attr row (f32)
    int    sc;
    bool   vld;
    {
        const int ge = tile * 64 + e;
        vld = (ge < E);
        if (vld) {
            const int row = srcrow[ge];
            const int eid = perm[ge];
            const uint4* xr = (const uint4*)(xb + (size_t)row * D_NODE) + qq * 4;
            xr0 = xr[0]; xr1 = xr[1]; xr2 = xr[2]; xr3 = xr[3];
            const float4* ar = (const float4*)(edge_attr + (size_t)eid * D_EDGE) + qq * 4;
            af0 = ar[0]; af1 = ar[1]; af2 = ar[2]; af3 = ar[3];
        }
        sc = (tid < 64 && tile * 64 + tid < E) ? dstcol[tile * 64 + tid] : -1;
    }

    for (; tile < ntiles; tile += stride_t) {
        // ---- staged regs -> h (wave-aligned rows; vmcnt wait lands here) ----
        if (vld) {
            *(uint4*)&h[e][qq * 32 +  0] = xr0;
            *(uint4*)&h[e][qq * 32 +  8] = xr1;
            *(uint4*)&h[e][qq * 32 + 16] = xr2;
            *(uint4*)&h[e][qq * 32 + 24] = xr3;
            uint4 o;
            o.x = pk2(af0.x, af0.y); o.y = pk2(af0.z, af0.w);
            o.z = pk2(af1.x, af1.y); o.w = pk2(af1.z, af1.w);
            *(uint4*)&h[e][128 + qq * 16] = o;
            o.x = pk2(af2.x, af2.y); o.y = pk2(af2.z, af2.w);
            o.z = pk2(af3.x, af3.y); o.w = pk2(af3.z, af3.w);
            *(uint4*)&h[e][128 + qq * 16 + 8] = o;
        } else {
            uint4 z = make_uint4(0u, 0u, 0u, 0u);
            *(uint4*)&h[e][qq * 32 +  0] = z;
            *(uint4*)&h[e][qq * 32 +  8] = z;
            *(uint4*)&h[e][qq * 32 + 16] = z;
            *(uint4*)&h[e][qq * 32 + 24] = z;
            *(uint4*)&h[e][128 + qq * 16]     = z;
            *(uint4*)&h[e][128 + qq * 16 + 8] = z;
        }
        if (tid < 64) scol2[pp][tid] = sc;
        __syncthreads();                       // B1: h + scol ready

        // ---- issue NEXT tile's gathers into registers (hide under compute) ----
        {
            const int nt = tile + stride_t;
            const int ge = nt * 64 + e;
            vld = (nt < ntiles) && (ge < E);
            if (vld) {
                const int row = srcrow[ge];
                const int eid = perm[ge];
                const uint4* xr = (const uint4*)(xb + (size_t)row * D_NODE) + qq * 4;
                xr0 = xr[0]; xr1 = xr[1]; xr2 = xr[2]; xr3 = xr[3];
                const float4* ar = (const float4*)(edge_attr + (size_t)eid * D_EDGE) + qq * 4;
                af0 = ar[0]; af1 = ar[1]; af2 = ar[2]; af3 = ar[3];
            }
            sc = (nt < ntiles && tid < 64 && nt * 64 + tid < E)
                   ? dstcol[nt * 64 + tid] : -1;
        }

        // ---- MFMA: 4 edge-tiles x 2 col-tiles, K=192 ----
        f32x4 acc[4][2];
        #pragma unroll
        for (int et = 0; et < 4; ++et)
            #pragma unroll
            for (int c2 = 0; c2 < 2; ++c2)
                acc[et][c2] = (f32x4){0.f, 0.f, 0.f, 0.f};

        #pragma unroll
        for (int et = 0; et < 4; ++et) {
            bf16x8 Afr[6];
            #pragma unroll
            for (int kt = 0; kt < 6; ++kt)
                Afr[kt] = *(const bf16x8*)&h[et * 16 + lm][kt * 32 + q8];
            #pragma unroll
            for (int c2 = 0; c2 < 2; ++c2)
                #pragma unroll
                for (int kt = 0; kt < 6; ++kt)
                    acc[et][c2] = __builtin_amdgcn_mfma_f32_16x16x32_bf16(
                        Afr[kt], Bfr[c2][kt], acc[et][c2], 0, 0, 0);
        }

        // ---- bias + LN partial sums ----
        #pragma unroll
        for (int et = 0; et < 4; ++et) {
            #pragma unroll
            for (int r = 0; r < 4; ++r) {
                float v0 = acc[et][0][r] + b1v[0];
                float v1 = acc[et][1][r] + b1v[1];
                acc[et][0][r] = v0;
                acc[et][1][r] = v1;
                float s  = v0 + v1;
                float s2 = v0 * v0 + v1 * v1;
                #pragma unroll
                for (int off = 1; off < 16; off <<= 1) {
                    s  += __shfl_xor(s,  off, 16);
                    s2 += __shfl_xor(s2, off, 16);
                }
                if (lm == 0) {
                    const int em = et * 16 + q * 4 + r;
                    rS [em][w] = s;
                    rS2[em][w] = s2;
                }
            }
        }
        __syncthreads();                       // B2: rS ready; ALL h reads done

        // ---- finalize LN + LeakyReLU, write y^T into PER-WAVE yT ----
        #pragma unroll
        for (int et = 0; et < 4; ++et) {
            float yv[2][4];
            #pragma unroll
            for (int r = 0; r < 4; ++r) {
                const int em = et * 16 + q * 4 + r;
                float4 p  = *(const float4*)&rS [em][0];
                float4 p2 = *(const float4*)&rS2[em][0];
                const float S    = (p.x  + p.y)  + (p.z  + p.w);
                const float S2   = (p2.x + p2.y) + (p2.z + p2.w);
                const float mu   = S * (1.f / 128.f);
                const float var  = S2 * (1.f / 128.f) - mu * mu;
                const float rstd = rsqrtf(var + LN_EPS);
                #pragma unroll
                for (int c2 = 0; c2 < 2; ++c2) {
                    float y = (acc[et][c2][r] - mu) * rstd * g1v[c2] + bev[c2];
                    y = (y > 0.f) ? y : NEG * y;
                    yv[c2][r] = y;
                }
            }
            #pragma unroll
            for (int c2 = 0; c2 < 2; ++c2) {
                const int cl = c2 * 16 + lm;            // col-local 0..31
                const int ch = ((et * 2 + (q >> 1)) ^ (lm & 7)) & 7;
                uint2 o;
                o.x = pk2(yv[c2][0], yv[c2][1]);
                o.y = pk2(yv[c2][2], yv[c2][3]);
                *(uint2*)&yT[cl][ch * 8 + (q & 1) * 4] = o;
            }
        }

        // ---- WAVE-LOCAL segmented reduce: D^T[col][run] ----
        {
            bf16x8 afr[2][2];
            #pragma unroll
            for (int ct = 0; ct < 2; ++ct)
                #pragma unroll
                for (int kt = 0; kt < 2; ++kt) {
                    const int cl = ct * 16 + lm;
                    const int ch = ((kt * 4 + q) ^ (lm & 7)) & 7;
                    afr[ct][kt] = *(const bf16x8*)&yT[cl][ch * 8];
                }

            // per-wave run metadata (every wave computes the same mask)
            int me = scol2[pp][l];
            int pv = __shfl_up(me, 1);
            if (l == 0) pv = me ^ 1;                    // force run start at 0
            const unsigned long long m = __ballot(me != pv);
            const int nr = (int)__popcll(m);
            const int rl = (int)__popcll(m & ((2ull << l) - 1)) - 1;
            if (me != pv) rdest[rl] = me;               // redundant across waves

            for (int rt = 0; rt * 16 < nr; ++rt) {
                const int rr = rt * 16 + lm;            // this lane's run (N dim)
                bf16x8 bb[2];
                #pragma unroll
                for (int kt = 0; kt < 2; ++kt) {
                    const int eb0 = kt * 32 + q8;
                    int rid = (int)__popcll(m & ((2ull << eb0) - 1)) - 1;
                    unsigned pk[4];
                    #pragma unroll
                    for (int jp = 0; jp < 4; ++jp) {
                        unsigned lo = (rid == rr) ? 0x3F80u : 0u;
                        rid += (int)((m >> (eb0 + 2 * jp + 1)) & 1ull);
                        unsigned hi = (rid == rr) ? 0x3F80u : 0u;
                        if (jp < 3) rid += (int)((m >> (eb0 + 2 * jp + 2)) & 1ull);
                        pk[jp] = lo | (hi << 16);
                    }
                    uint4 pku = make_uint4(pk[0], pk[1], pk[2], pk[3]);
                    bb[kt] = __builtin_bit_cast(bf16x8, pku);
                }
                f32x4 o0 = (f32x4){0.f, 0.f, 0.f, 0.f};
                f32x4 o1 = (f32x4){0.f, 0.f, 0.f, 0.f};
                #pragma unroll
                for (int kt = 0; kt < 2; ++kt) {
                    o0 = __builtin_amdgcn_mfma_f32_16x16x32_bf16(
                        afr[0][kt], bb[kt], o0, 0, 0, 0);
                    o1 = __builtin_amdgcn_mfma_f32_16x16x32_bf16(
                        afr[1][kt], bb[kt], o1, 0, 0, 0);
                }
                if (rr < nr) {
                    const int dest = rdest[rr];
                    if (dest >= 0) {
                        const bool at = (rr == 0) || (rr == nr - 1);
                        float* p0 = &sums[(size_t)dest * D_NODE + w * 32 + q * 4];
                        if (at) {
                            #pragma unroll
                            for (int r = 0; r < 4; ++r) {
                                atomicAdd(&p0[r],      o0[r]);
                                atomicAdd(&p0[16 + r], o1[r]);
                            }
                        } else {
                            *(f32x4*)p0        = o0;
                            *(f32x4*)(p0 + 16) = o1;
                        }
                    }
                }
            }
        }
        pp ^= 1;
        // no barrier: next staging touches only this wave's h rows and the
        // other scol parity buffer; rS rewrite is fenced by next B1+MFMA.
    }
}

// ---------------------------------------------------------------------------
// Node kernel (MFMA): m = sums/cnt -> y = m@W2+b2 -> LN -> LeakyReLU
//                     -> +x -> LeakyReLU -> out.  64-node tiles.
// ---------------------------------------------------------------------------
__global__ __launch_bounds__(256) void node_mfma(
    const float* __restrict__ sums,
    const int*   __restrict__ hist,
    const float* __restrict__ x,
    const float* __restrict__ W2,
    const float* __restrict__ b2,
    const float* __restrict__ g2,
    const float* __restrict__ be2,
    float* __restrict__ out,
    int N)
{
    __shared__ __align__(16) unsigned short h[64][136];     // 17.4 KB
    __shared__ float rS [64][4], rS2[64][4];

    const int tid = threadIdx.x;
    const int w   = tid >> 6;
    const int l   = tid & 63;
    const int lm  = l & 15;
    const int q   = l >> 4;
    const int q8  = q * 8;

    bf16x8 Bfr[2][4];
    float  b2v[2], g2v[2], bev[2];
    #pragma unroll
    for (int c2 = 0; c2 < 2; ++c2) {
        const int n = (2 * w + c2) * 16 + lm;
        b2v[c2] = b2[n]; g2v[c2] = g2[n]; bev[c2] = be2[n];
        #pragma unroll
        for (int kt = 0; kt < 4; ++kt) {
            bf16x8 f;
            #pragma unroll
            for (int j = 0; j < 8; ++j)
                f[j] = (short)f2bf(W2[(kt * 32 + q8 + j) * 128 + n]);
            Bfr[c2][kt] = f;
        }
    }

    const int n0 = blockIdx.x * 64;

    // stage m = sums/cnt (bf16)
    {
        const int e  = tid >> 2;
        const int qq = tid & 3;
        const int gn = n0 + e;
        if (gn < N) {
            const int cnt = hist[gn];
            const float sc = (cnt > 0) ? 1.f / (float)cnt : 0.f;
            const float4* sr = (const float4*)(sums + (size_t)gn * D_NODE);
            #pragma unroll
            for (int i = 0; i < 8; ++i) {
                float4 v = sr[qq * 8 + i];
                *(uint2*)&h[e][qq * 32 + i * 4] =
                    make_uint2(pk2(v.x * sc, v.y * sc), pk2(v.z * sc, v.w * sc));
            }
        } else {
            #pragma unroll
            for (int i = 0; i < 8; ++i)
                *(uint2*)&h[e][qq * 32 + i * 4] = make_uint2(0u, 0u);
        }
    }
    __syncthreads();

    f32x4 acc[4][2];
    #pragma unroll
    for (int et = 0; et < 4; ++et)
        #pragma unroll
        for (int c2 = 0; c2 < 2; ++c2)
            acc[et][c2] = (f32x4){0.f, 0.f, 0.f, 0.f};

    #pragma unroll
    for (int et = 0; et < 4; ++et) {
        bf16x8 Afr[4];
        #pragma unroll
        for (int kt = 0; kt < 4; ++kt)
            Afr[kt] = *(const bf16x8*)&h[et * 16 + lm][kt * 32 + q8];
        #pragma unroll
        for (int c2 = 0; c2 < 2; ++c2)
            #pragma unroll
            for (int kt = 0; kt < 4; ++kt)
                acc[et][c2] = __builtin_amdgcn_mfma_f32_16x16x32_bf16(
                    Afr[kt], Bfr[c2][kt], acc[et][c2], 0, 0, 0);
    }

    #pragma unroll
    for (int et = 0; et < 4; ++et) {
        #pragma unroll
        for (int r = 0; r < 4; ++r) {
            float v0 = acc[et][0][r] + b2v[0];
            float v1 = acc[et][1][r] + b2v[1];
            acc[et][0][r] = v0;
            acc[et][1][r] = v1;
            float s  = v0 + v1;
            float s2 = v0 * v0 + v1 * v1;
            #pragma unroll
            for (int off = 1; off < 16; off <<= 1) {
                s  += __shfl_xor(s,  off, 16);
                s2 += __shfl_xor(s2, off, 16);
            }
            if (lm == 0) {
                const int em = et * 16 + q * 4 + r;
                rS [em][w] = s;
                rS2[em][w] = s2;
            }
        }
    }
    __syncthreads();

    #pragma unroll
    for (int et = 0; et < 4; ++et) {
        #pragma unroll
        for (int r = 0; r < 4; ++r) {
            const int em = et * 16 + q * 4 + r;
            const int gn = n0 + em;
            if (gn >= N) continue;
            float4 p  = *(const float4*)&rS [em][0];
            float4 p2 = *(const float4*)&rS2[em][0];
            const float S    = (p.x  + p.y)  + (p.z  + p.w);
            const float S2   = (p2.x + p2.y) + (p2.z + p2.w);
            const float mu   = S * (1.f / 128.f);
            const float var  = S2 * (1.f / 128.f) - mu * mu;
            const float rstd = rsqrtf(var + LN_EPS);
            #pragma unroll
            for (int c2 = 0; c2 < 2; ++c2) {
                const int col = (2 * w + c2) * 16 + lm;
                float y = (acc[et][c2][r] - mu) * rstd * g2v[c2] + bev[c2];
                y = (y > 0.f) ? y : NEG * y;
                float rr = y + x[(size_t)gn * D_NODE + col];
                rr = (rr > 0.f) ? rr : NEG * rr;
                out[(size_t)gn * D_NODE + col] = rr;
            }
        }
    }
}

// ---------------------------------------------------------------------------
extern "C" void kernel_launch(void* const* d_in, const int* in_sizes, int n_in,
                              void* d_out, int out_size, void* d_ws, size_t ws_size,
                              hipStream_t stream) {
    const float* x          = (const float*)d_in[0];
    const int*   edge_index = (const int*)  d_in[1];
    const float* edge_attr  = (const float*)d_in[2];
    const float* W1         = (const float*)d_in[3];
    const float* b1         = (const float*)d_in[4];
    const float* g1         = (const float*)d_in[5];
    const float* be1        = (const float*)d_in[6];
    const float* W2         = (const float*)d_in[7];
    const float* b2         = (const float*)d_in[8];
    const float* g2         = (const float*)d_in[9];
    const float* be2        = (const float*)d_in[10];

    const int N = in_sizes[0] / D_NODE;     // 50000
    const int E = in_sizes[1] / 2;          // 600000

    float* sums     = (float*)d_ws;                        // N*128 f32
    int*   hist     = (int*)(sums + (size_t)N * D_NODE);   // N
    int*   base     = hist + N;                            // N
    int*   blockTot = base + N;                            // 64
    int*   perm     = blockTot + 64;                       // E
    int*   srcrow   = perm + E;                            // E
    int*   dstcol   = srcrow + E;                          // E
    unsigned short* xb = (unsigned short*)(dstcol + E);    // N*128 bf16 (~46 MB total)

    // zero sums + hist in one shot
    hipMemsetAsync(d_ws, 0, ((size_t)N * D_NODE + (size_t)N) * sizeof(float), stream);

    const int n8 = N * (D_NODE / 8);
    k_packx<<<dim3(1024), dim3(256), 0, stream>>>(x, xb, n8);

    k_hist<<<dim3(256), dim3(256), 0, stream>>>(edge_index, hist, E);
    const int NB = (N + 1023) / 1024;                      // 49 (<=64)
    k_scanA<<<dim3(NB), dim3(1024), 0, stream>>>(hist, base, blockTot, N);
    k_scanB<<<dim3(1),  dim3(64),   0, stream>>>(blockTot, NB);
    k_scanC<<<dim3(NB), dim3(1024), 0, stream>>>(base, blockTot, N);
    k_bucket<<<dim3(256), dim3(256), 0, stream>>>(edge_index, base, perm, srcrow, dstcol, E);

    const int ntiles = (E + 63) / 64;
    const int grid   = ntiles < 1024 ? ntiles : 1024;      // 4 blocks/CU
    edge_mfma_seg<<<dim3(grid), dim3(256), 0, stream>>>(
        xb, edge_attr, perm, srcrow, dstcol, W1, b1, g1, be1, sums, E, ntiles);

    node_mfma<<<dim3((N + 63) / 64), dim3(256), 0, stream>>>(
        sums, hist, x, W2, b2, g2, be2, (float*)d_out, N);
}

// Round 6
// 440.488 us; speedup vs baseline: 1.6624x; 1.1053x over previous
//
#include <hip/hip_runtime.h>

#define D_NODE 128
#define D_EDGE 64
#define D_IN   192
#define NEG    0.01f
#define LN_EPS 1e-5f

typedef short bf16x8 __attribute__((ext_vector_type(8)));
typedef float f32x4  __attribute__((ext_vector_type(4)));

__device__ __forceinline__ unsigned f2bf(float f) {
    unsigned u = __builtin_bit_cast(unsigned, f);
    return (u + 0x7FFFu + ((u >> 16) & 1u)) >> 16;   // RNE
}
__device__ __forceinline__ unsigned pk2(float a, float b) {
    return f2bf(a) | (f2bf(b) << 16);
}
// HW packed f32->bf16 (RNE), 1 instr for 2 values (no builtin on gfx950)
__device__ __forceinline__ unsigned cvtpk(float a, float b) {
    unsigned r;
    asm("v_cvt_pk_bf16_f32 %0, %1, %2" : "=v"(r) : "v"(a), "v"(b));
    return r;
}
// 16-lane sum via DPP (pure VALU, no LDS routing):
// xor1=quad_perm{1,0,3,2}=0xB1, xor2=quad_perm{2,3,0,1}=0x4E,
// 8-swap=row_half_mirror=0x141, 16-swap=row_mirror=0x140.
template <int C>
__device__ __forceinline__ float dppadd(float v) {
    int y = __builtin_amdgcn_update_dpp(0, __builtin_bit_cast(int, v),
                                        C, 0xF, 0xF, true);
    return v + __builtin_bit_cast(float, y);
}
__device__ __forceinline__ float red16(float v) {
    v = dppadd<0xB1>(v);
    v = dppadd<0x4E>(v);
    v = dppadd<0x141>(v);
    v = dppadd<0x140>(v);
    return v;
}

// ---------------------------------------------------------------------------
// Pre-pack x (N x 128 f32) -> bf16 once.
// ---------------------------------------------------------------------------
__global__ void k_packx(const float* __restrict__ x, unsigned short* __restrict__ xb,
                        int n8) {
    int i = blockIdx.x * blockDim.x + threadIdx.x;
    int stride = gridDim.x * blockDim.x;
    for (int t = i; t < n8; t += stride) {
        const float4* p = (const float4*)x + (size_t)t * 2;
        float4 a = p[0], b = p[1];
        uint4 o;
        o.x = pk2(a.x, a.y); o.y = pk2(a.z, a.w);
        o.z = pk2(b.x, b.y); o.w = pk2(b.z, b.w);
        ((uint4*)xb)[t] = o;
    }
}

// ---------------------------------------------------------------------------
// Counting sort of edges by destination: hist -> exclusive scan -> bucket.
// ---------------------------------------------------------------------------
__global__ void k_hist(const int* __restrict__ ei, int* __restrict__ hist, int E) {
    int i = blockIdx.x * blockDim.x + threadIdx.x;
    int stride = gridDim.x * blockDim.x;
    for (int e = i; e < E; e += stride) atomicAdd(&hist[ei[E + e]], 1);
}

__global__ __launch_bounds__(1024) void k_scanA(const int* __restrict__ hist,
                                                int* __restrict__ base,
                                                int* __restrict__ blockTot, int N) {
    __shared__ int wsum[16], woff[16];
    const int t = threadIdx.x, b = blockIdx.x;
    const int i = b * 1024 + t;
    const int lane = t & 63, w = t >> 6;
    int v = (i < N) ? hist[i] : 0;
    int x = v;
    #pragma unroll
    for (int d = 1; d < 64; d <<= 1) { int u = __shfl_up(x, d); if (lane >= d) x += u; }
    if (lane == 63) wsum[w] = x;
    __syncthreads();
    if (t < 16) {
        int y = wsum[t];
        #pragma unroll
        for (int d = 1; d < 16; d <<= 1) { int u = __shfl_up(y, d, 16); if (t >= d) y += u; }
        woff[t] = y - wsum[t];
    }
    __syncthreads();
    int incl = x + woff[w];
    if (i < N) base[i] = incl - v;            // exclusive within block
    if (t == 1023) blockTot[b] = incl;
}

__global__ void k_scanB(int* __restrict__ blockTot, int NB) {   // 1 block, 64 thr, NB<=64
    int t = threadIdx.x;
    int v = (t < NB) ? blockTot[t] : 0;
    int x = v;
    #pragma unroll
    for (int d = 1; d < 64; d <<= 1) { int u = __shfl_up(x, d); if (t >= d) x += u; }
    if (t < NB) blockTot[t] = x - v;          // exclusive block offsets
}

__global__ __launch_bounds__(1024) void k_scanC(int* __restrict__ base,
                                                const int* __restrict__ blockTot, int N) {
    int i = blockIdx.x * 1024 + threadIdx.x;
    if (i < N) base[i] += blockTot[blockIdx.x];
}

// meta[p] = (srcrow, dstcol, eid, 0): ONE 16B scattered store per edge
// (1 RFO line) instead of 3 separate 4B stores (3 lines).
__global__ void k_bucket(const int* __restrict__ ei, int* __restrict__ base,
                         int4* __restrict__ meta, int E) {
    int i = blockIdx.x * blockDim.x + threadIdx.x;
    int stride = gridDim.x * blockDim.x;
    for (int e = i; e < E; e += stride) {
        int c = ei[E + e];
        int r = ei[e];
        int p = atomicAdd(&base[c], 1);       // consumes base (cursor)
        meta[p] = make_int4(r, c, e, 0);
    }
}

// ---------------------------------------------------------------------------
// Edge kernel, 2-barrier pipeline + register prefetch (round-4/5 structure):
//   B1: staged h + scol visible.  B2: rS (LN partials) visible + h consumed.
//   Post-B2 is wave-local (per-wave yT aliased onto own h rows; P^T built in
//   registers from per-wave ballot).  This round: DPP LN reduce (no LDS
//   routing), v_cvt_pk_bf16_f32 packing, int4 meta loads.
// ---------------------------------------------------------------------------
__global__ __launch_bounds__(256) void edge_mfma_seg(
    const unsigned short* __restrict__ xb,
    const float* __restrict__ edge_attr,
    const int4*  __restrict__ meta,
    const float* __restrict__ W1,
    const float* __restrict__ b1,
    const float* __restrict__ g1,
    const float* __restrict__ be1,
    float* __restrict__ sums,
    int E, int ntiles)
{
    __shared__ __align__(16) unsigned short h[64][200];   // 25.6 KB
    __shared__ float rS [64][4], rS2[64][4];
    __shared__ int   scol2[2][64];
    __shared__ int   rdest[64];

    const int tid = threadIdx.x;
    const int w   = tid >> 6;
    const int l   = tid & 63;
    const int lm  = l & 15;
    const int q   = l >> 4;
    const int q8  = q * 8;
    const int e   = tid >> 2;                 // = 16w + (l>>2): wave-aligned rows
    const int qq  = tid & 3;

    // per-wave yT region: 32 cols x 64 edges bf16 (4KB), aliased onto the
    // wave's own h rows [16w,16w+16) — dead after B2.
    unsigned short (*yT)[64] = (unsigned short (*)[64])(&h[w * 16][0]);

    // W1 fragments, bias/gamma/beta for this wave's 32 cols (once per block)
    bf16x8 Bfr[2][6];
    float  b1v[2], g1v[2], bev[2];
    #pragma unroll
    for (int c2 = 0; c2 < 2; ++c2) {
        const int n = (2 * w + c2) * 16 + lm;
        b1v[c2] = b1[n]; g1v[c2] = g1[n]; bev[c2] = be1[n];
        #pragma unroll
        for (int kt = 0; kt < 6; ++kt) {
            bf16x8 f;
            #pragma unroll
            for (int j = 0; j < 8; ++j)
                f[j] = (short)f2bf(W1[(kt * 32 + q8 + j) * 128 + n]);
            Bfr[c2][kt] = f;
        }
    }

    const int stride_t = gridDim.x;
    int tile = blockIdx.x;                    // < ntiles (grid is clamped)
    int pp   = 0;                             // scol parity

    // ---- prologue: stage tile `tile` into registers ----
    uint4  xr0, xr1, xr2, xr3;                // 16 VGPR: x row (bf16)
    float4 af0, af1, af2, af3;                // 16 VGPR: edge_attr row (f32)
    int    sc;
    bool   vld;
    {
        const int ge = tile * 64 + e;
        vld = (ge < E);
        if (vld) {
            const int4 mt = meta[ge];
            const uint4* xr = (const uint4*)(xb + (size_t)mt.x * D_NODE) + qq * 4;
            xr0 = xr[0]; xr1 = xr[1]; xr2 = xr[2]; xr3 = xr[3];
            const float4* ar = (const float4*)(edge_attr + (size_t)mt.z * D_EDGE) + qq * 4;
            af0 = ar[0]; af1 = ar[1]; af2 = ar[2]; af3 = ar[3];
        }
        sc = (tid < 64 && tile * 64 + tid < E) ? meta[tile * 64 + tid].y : -1;
    }

    for (; tile < ntiles; tile += stride_t) {
        // ---- staged regs -> h (wave-aligned rows; vmcnt wait lands here) ----
        if (vld) {
            *(uint4*)&h[e][qq * 32 +  0] = xr0;
            *(uint4*)&h[e][qq * 32 +  8] = xr1;
            *(uint4*)&h[e][qq * 32 + 16] = xr2;
            *(uint4*)&h[e][qq * 32 + 24] = xr3;
            uint4 o;
            o.x = cvtpk(af0.x, af0.y); o.y = cvtpk(af0.z, af0.w);
            o.z = cvtpk(af1.x, af1.y); o.w = cvtpk(af1.z, af1.w);
            *(uint4*)&h[e][128 + qq * 16] = o;
            o.x = cvtpk(af2.x, af2.y); o.y = cvtpk(af2.z, af2.w);
            o.z = cvtpk(af3.x, af3.y); o.w = cvtpk(af3.z, af3.w);
            *(uint4*)&h[e][128 + qq * 16 + 8] = o;
        } else {
            uint4 z = make_uint4(0u, 0u, 0u, 0u);
            *(uint4*)&h[e][qq * 32 +  0] = z;
            *(uint4*)&h[e][qq * 32 +  8] = z;
            *(uint4*)&h[e][qq * 32 + 16] = z;
            *(uint4*)&h[e][qq * 32 + 24] = z;
            *(uint4*)&h[e][128 + qq * 16]     = z;
            *(uint4*)&h[e][128 + qq * 16 + 8] = z;
        }
        if (tid < 64) scol2[pp][tid] = sc;
        __syncthreads();                       // B1: h + scol ready

        // ---- issue NEXT tile's gathers into registers (hide under compute) ----
        {
            const int nt = tile + stride_t;
            const int ge = nt * 64 + e;
            vld = (nt < ntiles) && (ge < E);
            if (vld) {
                const int4 mt = meta[ge];
                const uint4* xr = (const uint4*)(xb + (size_t)mt.x * D_NODE) + qq * 4;
                xr0 = xr[0]; xr1 = xr[1]; xr2 = xr[2]; xr3 = xr[3];
                const float4* ar = (const float4*)(edge_attr + (size_t)mt.z * D_EDGE) + qq * 4;
                af0 = ar[0]; af1 = ar[1]; af2 = ar[2]; af3 = ar[3];
            }
            sc = (nt < ntiles && tid < 64 && nt * 64 + tid < E)
                   ? meta[nt * 64 + tid].y : -1;
        }

        // ---- MFMA: 4 edge-tiles x 2 col-tiles, K=192 ----
        f32x4 acc[4][2];
        #pragma unroll
        for (int et = 0; et < 4; ++et)
            #pragma unroll
            for (int c2 = 0; c2 < 2; ++c2)
                acc[et][c2] = (f32x4){0.f, 0.f, 0.f, 0.f};

        #pragma unroll
        for (int et = 0; et < 4; ++et) {
            bf16x8 Afr[6];
            #pragma unroll
            for (int kt = 0; kt < 6; ++kt)
                Afr[kt] = *(const bf16x8*)&h[et * 16 + lm][kt * 32 + q8];
            #pragma unroll
            for (int c2 = 0; c2 < 2; ++c2)
                #pragma unroll
                for (int kt = 0; kt < 6; ++kt)
                    acc[et][c2] = __builtin_amdgcn_mfma_f32_16x16x32_bf16(
                        Afr[kt], Bfr[c2][kt], acc[et][c2], 0, 0, 0);
        }

        // ---- bias + LN partial sums (DPP 16-lane reduce, no LDS routing) ----
        #pragma unroll
        for (int et = 0; et < 4; ++et) {
            #pragma unroll
            for (int r = 0; r < 4; ++r) {
                float v0 = acc[et][0][r] + b1v[0];
                float v1 = acc[et][1][r] + b1v[1];
                acc[et][0][r] = v0;
                acc[et][1][r] = v1;
                float s  = red16(v0 + v1);
                float s2 = red16(v0 * v0 + v1 * v1);
                if (lm == 0) {
                    const int em = et * 16 + q * 4 + r;
                    rS [em][w] = s;
                    rS2[em][w] = s2;
                }
            }
        }
        __syncthreads();                       // B2: rS ready; ALL h reads done

        // ---- finalize LN + LeakyReLU, write y^T into PER-WAVE yT ----
        #pragma unroll
        for (int et = 0; et < 4; ++et) {
            float yv[2][4];
            #pragma unroll
            for (int r = 0; r < 4; ++r) {
                const int em = et * 16 + q * 4 + r;
                float4 p  = *(const float4*)&rS [em][0];
                float4 p2 = *(const float4*)&rS2[em][0];
                const float S    = (p.x  + p.y)  + (p.z  + p.w);
                const float S2   = (p2.x + p2.y) + (p2.z + p2.w);
                const float mu   = S * (1.f / 128.f);
                const float var  = S2 * (1.f / 128.f) - mu * mu;
                const float rstd = rsqrtf(var + LN_EPS);
                #pragma unroll
                for (int c2 = 0; c2 < 2; ++c2) {
                    float y = (acc[et][c2][r] - mu) * rstd * g1v[c2] + bev[c2];
                    y = (y > 0.f) ? y : NEG * y;
                    yv[c2][r] = y;
                }
            }
            #pragma unroll
            for (int c2 = 0; c2 < 2; ++c2) {
                const int cl = c2 * 16 + lm;            // col-local 0..31
                const int ch = ((et * 2 + (q >> 1)) ^ (lm & 7)) & 7;
                uint2 o;
                o.x = cvtpk(yv[c2][0], yv[c2][1]);
                o.y = cvtpk(yv[c2][2], yv[c2][3]);
                *(uint2*)&yT[cl][ch * 8 + (q & 1) * 4] = o;
            }
        }

        // ---- WAVE-LOCAL segmented reduce: D^T[col][run] ----
        {
            bf16x8 afr[2][2];
            #pragma unroll
            for (int ct = 0; ct < 2; ++ct)
                #pragma unroll
                for (int kt = 0; kt < 2; ++kt) {
                    const int cl = ct * 16 + lm;
                    const int ch = ((kt * 4 + q) ^ (lm & 7)) & 7;
                    afr[ct][kt] = *(const bf16x8*)&yT[cl][ch * 8];
                }

            // per-wave run metadata (every wave computes the same mask)
            int me = scol2[pp][l];
            int pv = __shfl_up(me, 1);
            if (l == 0) pv = me ^ 1;                    // force run start at 0
            const unsigned long long m = __ballot(me != pv);
            const int nr = (int)__popcll(m);
            const int rl = (int)__popcll(m & ((2ull << l) - 1)) - 1;
            if (me != pv) rdest[rl] = me;               // redundant across waves

            for (int rt = 0; rt * 16 < nr; ++rt) {
                const int rr = rt * 16 + lm;            // this lane's run (N dim)
                bf16x8 bb[2];
                #pragma unroll
                for (int kt = 0; kt < 2; ++kt) {
                    const int eb0 = kt * 32 + q8;
                    int rid = (int)__popcll(m & ((2ull << eb0) - 1)) - 1;
                    unsigned pk[4];
                    #pragma unroll
                    for (int jp = 0; jp < 4; ++jp) {
                        unsigned lo = (rid == rr) ? 0x3F80u : 0u;
                        rid += (int)((m >> (eb0 + 2 * jp + 1)) & 1ull);
                        unsigned hi = (rid == rr) ? 0x3F80u : 0u;
                        if (jp < 3) rid += (int)((m >> (eb0 + 2 * jp + 2)) & 1ull);
                        pk[jp] = lo | (hi << 16);
                    }
                    uint4 pku = make_uint4(pk[0], pk[1], pk[2], pk[3]);
                    bb[kt] = __builtin_bit_cast(bf16x8, pku);
                }
                f32x4 o0 = (f32x4){0.f, 0.f, 0.f, 0.f};
                f32x4 o1 = (f32x4){0.f, 0.f, 0.f, 0.f};
                #pragma unroll
                for (int kt = 0; kt < 2; ++kt) {
                    o0 = __builtin_amdgcn_mfma_f32_16x16x32_bf16(
                        afr[0][kt], bb[kt], o0, 0, 0, 0);
                    o1 = __builtin_amdgcn_mfma_f32_16x16x32_bf16(
                        afr[1][kt], bb[kt], o1, 0, 0, 0);
                }
                if (rr < nr) {
                    const int dest = rdest[rr];
                    if (dest >= 0) {
                        const bool at = (rr == 0) || (rr == nr - 1);
                        float* p0 = &sums[(size_t)dest * D_NODE + w * 32 + q * 4];
                        if (at) {
                            #pragma unroll
                            for (int r = 0; r < 4; ++r) {
                                atomicAdd(&p0[r],      o0[r]);
                                atomicAdd(&p0[16 + r], o1[r]);
                            }
                        } else {
                            *(f32x4*)p0        = o0;
                            *(f32x4*)(p0 + 16) = o1;
                        }
                    }
                }
            }
        }
        pp ^= 1;
        // no barrier: next staging touches only this wave's h rows and the
        // other scol parity buffer; rS rewrite is fenced by next B1+MFMA.
    }
}

// ---------------------------------------------------------------------------
// Node kernel (MFMA): m = sums/cnt -> y = m@W2+b2 -> LN -> LeakyReLU
//                     -> +x -> LeakyReLU -> out.  64-node tiles.
// ---------------------------------------------------------------------------
__global__ __launch_bounds__(256) void node_mfma(
    const float* __restrict__ sums,
    const int*   __restrict__ hist,
    const float* __restrict__ x,
    const float* __restrict__ W2,
    const float* __restrict__ b2,
    const float* __restrict__ g2,
    const float* __restrict__ be2,
    float* __restrict__ out,
    int N)
{
    __shared__ __align__(16) unsigned short h[64][136];     // 17.4 KB
    __shared__ float rS [64][4], rS2[64][4];

    const int tid = threadIdx.x;
    const int w   = tid >> 6;
    const int l   = tid & 63;
    const int lm  = l & 15;
    const int q   = l >> 4;
    const int q8  = q * 8;

    bf16x8 Bfr[2][4];
    float  b2v[2], g2v[2], bev[2];
    #pragma unroll
    for (int c2 = 0; c2 < 2; ++c2) {
        const int n = (2 * w + c2) * 16 + lm;
        b2v[c2] = b2[n]; g2v[c2] = g2[n]; bev[c2] = be2[n];
        #pragma unroll
        for (int kt = 0; kt < 4; ++kt) {
            bf16x8 f;
            #pragma unroll
            for (int j = 0; j < 8; ++j)
                f[j] = (short)f2bf(W2[(kt * 32 + q8 + j) * 128 + n]);
            Bfr[c2][kt] = f;
        }
    }

    const int n0 = blockIdx.x * 64;

    // stage m = sums/cnt (bf16)
    {
        const int e  = tid >> 2;
        const int qq = tid & 3;
        const int gn = n0 + e;
        if (gn < N) {
            const int cnt = hist[gn];
            const float sc = (cnt > 0) ? 1.f / (float)cnt : 0.f;
            const float4* sr = (const float4*)(sums + (size_t)gn * D_NODE);
            #pragma unroll
            for (int i = 0; i < 8; ++i) {
                float4 v = sr[qq * 8 + i];
                *(uint2*)&h[e][qq * 32 + i * 4] =
                    make_uint2(cvtpk(v.x * sc, v.y * sc), cvtpk(v.z * sc, v.w * sc));
            }
        } else {
            #pragma unroll
            for (int i = 0; i < 8; ++i)
                *(uint2*)&h[e][qq * 32 + i * 4] = make_uint2(0u, 0u);
        }
    }
    __syncthreads();

    f32x4 acc[4][2];
    #pragma unroll
    for (int et = 0; et < 4; ++et)
        #pragma unroll
        for (int c2 = 0; c2 < 2; ++c2)
            acc[et][c2] = (f32x4){0.f, 0.f, 0.f, 0.f};

    #pragma unroll
    for (int et = 0; et < 4; ++et) {
        bf16x8 Afr[4];
        #pragma unroll
        for (int kt = 0; kt < 4; ++kt)
            Afr[kt] = *(const bf16x8*)&h[et * 16 + lm][kt * 32 + q8];
        #pragma unroll
        for (int c2 = 0; c2 < 2; ++c2)
            #pragma unroll
            for (int kt = 0; kt < 4; ++kt)
                acc[et][c2] = __builtin_amdgcn_mfma_f32_16x16x32_bf16(
                    Afr[kt], Bfr[c2][kt], acc[et][c2], 0, 0, 0);
    }

    #pragma unroll
    for (int et = 0; et < 4; ++et) {
        #pragma unroll
        for (int r = 0; r < 4; ++r) {
            float v0 = acc[et][0][r] + b2v[0];
            float v1 = acc[et][1][r] + b2v[1];
            acc[et][0][r] = v0;
            acc[et][1][r] = v1;
            float s  = red16(v0 + v1);
            float s2 = red16(v0 * v0 + v1 * v1);
            if (lm == 0) {
                const int em = et * 16 + q * 4 + r;
                rS [em][w] = s;
                rS2[em][w] = s2;
            }
        }
    }
    __syncthreads();

    #pragma unroll
    for (int et = 0; et < 4; ++et) {
        #pragma unroll
        for (int r = 0; r < 4; ++r) {
            const int em = et * 16 + q * 4 + r;
            const int gn = n0 + em;
            if (gn >= N) continue;
            float4 p  = *(const float4*)&rS [em][0];
            float4 p2 = *(const float4*)&rS2[em][0];
            const float S    = (p.x  + p.y)  + (p.z  + p.w);
            const float S2   = (p2.x + p2.y) + (p2.z + p2.w);
            const float mu   = S * (1.f / 128.f);
            const float var  = S2 * (1.f / 128.f) - mu * mu;
            const float rstd = rsqrtf(var + LN_EPS);
            #pragma unroll
            for (int c2 = 0; c2 < 2; ++c2) {
                const int col = (2 * w + c2) * 16 + lm;
                float y = (acc[et][c2][r] - mu) * rstd * g2v[c2] + bev[c2];
                y = (y > 0.f) ? y : NEG * y;
                float rr = y + x[(size_t)gn * D_NODE + col];
                rr = (rr > 0.f) ? rr : NEG * rr;
                out[(size_t)gn * D_NODE + col] = rr;
            }
        }
    }
}

// ---------------------------------------------------------------------------
extern "C" void kernel_launch(void* const* d_in, const int* in_sizes, int n_in,
                              void* d_out, int out_size, void* d_ws, size_t ws_size,
                              hipStream_t stream) {
    const float* x          = (const float*)d_in[0];
    const int*   edge_index = (const int*)  d_in[1];
    const float* edge_attr  = (const float*)d_in[2];
    const float* W1         = (const float*)d_in[3];
    const float* b1         = (const float*)d_in[4];
    const float* g1         = (const float*)d_in[5];
    const float* be1        = (const float*)d_in[6];
    const float* W2         = (const float*)d_in[7];
    const float* b2         = (const float*)d_in[8];
    const float* g2         = (const float*)d_in[9];
    const float* be2        = (const float*)d_in[10];

    const int N = in_sizes[0] / D_NODE;     // 50000
    const int E = in_sizes[1] / 2;          // 600000

    float* sums     = (float*)d_ws;                        // N*128 f32
    int*   hist     = (int*)(sums + (size_t)N * D_NODE);   // N
    int*   base     = hist + N;                            // N
    int*   blockTot = base + N;                            // 64
    int4*  meta     = (int4*)(blockTot + 64);              // E int4 (16B aligned)
    unsigned short* xb = (unsigned short*)(meta + E);      // N*128 bf16

    // zero sums + hist in one shot
    hipMemsetAsync(d_ws, 0, ((size_t)N * D_NODE + (size_t)N) * sizeof(float), stream);

    const int n8 = N * (D_NODE / 8);
    k_packx<<<dim3(1024), dim3(256), 0, stream>>>(x, xb, n8);

    k_hist<<<dim3(256), dim3(256), 0, stream>>>(edge_index, hist, E);
    const int NB = (N + 1023) / 1024;                      // 49 (<=64)
    k_scanA<<<dim3(NB), dim3(1024), 0, stream>>>(hist, base, blockTot, N);
    k_scanB<<<dim3(1),  dim3(64),   0, stream>>>(blockTot, NB);
    k_scanC<<<dim3(NB), dim3(1024), 0, stream>>>(base, blockTot, N);
    k_bucket<<<dim3(256), dim3(256), 0, stream>>>(edge_index, base, meta, E);

    const int ntiles = (E + 63) / 64;
    const int grid   = ntiles < 1024 ? ntiles : 1024;      // 4 blocks/CU
    edge_mfma_seg<<<dim3(grid), dim3(256), 0, stream>>>(
        xb, edge_attr, meta, W1, b1, g1, be1, sums, E, ntiles);

    node_mfma<<<dim3((N + 63) / 64), dim3(256), 0, stream>>>(
        sums, hist, x, W2, b2, g2, be2, (float*)d_out, N);
}